// Round 13
// baseline (2804.150 us; speedup 1.0000x reference)
//
#include <hip/hip_runtime.h>
#include <math.h>

#define AA 32
#define BB 2048
#define BP1 2049
#define CC 256
#define NROWS (AA * BP1)          // 65568
#define NBLK 3
#define FFN 1024

typedef unsigned int uint;
typedef unsigned short ushort_t;
typedef __attribute__((ext_vector_type(4))) float f32x4;
typedef __attribute__((ext_vector_type(8))) short short8;

// epilogue flag bits for mm_k (wave-uniform runtime flags)
#define F_ROWMAP 2
#define F_BIAS2D 4
#define F_BIAS1D 8
#define F_GELU   16
#define F_RESID  32
#define F_OUTB16 64
#define F_QKV    128
#define F_LN     256

__device__ __forceinline__ float bf2f(ushort_t u) {
    return __uint_as_float(((uint)u) << 16);
}
__device__ __forceinline__ ushort_t f2b(float x) {   // fp32 -> bf16 RNE
    uint u = __float_as_uint(x);
    u += 0x7fff + ((u >> 16) & 1);
    return (ushort_t)(u >> 16);
}

// global -> LDS direct 16B load
typedef const uint __attribute__((address_space(1)))* gas_t;
typedef uint __attribute__((address_space(3)))* las_t;
__device__ __forceinline__ void gload16(const ushort_t* g, const short* l) {
    __builtin_amdgcn_global_load_lds(
        reinterpret_cast<gas_t>(reinterpret_cast<uintptr_t>(g)),
        reinterpret_cast<las_t>(static_cast<uint>(reinterpret_cast<uintptr_t>(l))),
        16, 0, 0);
}

// ---------------- fp32 -> two bf16 planes (hi, lo) ----------------
__global__ __launch_bounds__(256) void pack2_k(const float* __restrict__ src,
                                               ushort_t* __restrict__ dh,
                                               ushort_t* __restrict__ dl, int n) {
    int i = blockIdx.x * 256 + threadIdx.x;
    if (i < n) {
        float v = src[i];
        ushort_t h = f2b(v);
        dh[i] = h;
        dl[i] = f2b(v - bf2f(h));
    }
}

// ---------------- row 0 of each batch: cls + bias, then LN1 -> z planes ----------------
__global__ __launch_bounds__(64) void row0_k(float* __restrict__ out,
                                             const float* __restrict__ cls,
                                             const float* __restrict__ bias,
                                             const float* __restrict__ lng,
                                             const float* __restrict__ lnb,
                                             ushort_t* __restrict__ zh,
                                             ushort_t* __restrict__ zl) {
    int i = blockIdx.x, l = threadIdx.x;
    size_t base = (size_t)i * BP1 * CC;           // row g0 = i*BP1
    const float4 c = *reinterpret_cast<const float4*>(cls + i * CC + l * 4);
    const float4 b = *reinterpret_cast<const float4*>(bias + base + l * 4);
    float v0 = c.x + b.x, v1 = c.y + b.y, v2 = c.z + b.z, v3 = c.w + b.w;
    *reinterpret_cast<float4*>(out + base + l * 4) = make_float4(v0, v1, v2, v3);
    float s = v0 + v1 + v2 + v3;
    float sq = v0 * v0 + v1 * v1 + v2 * v2 + v3 * v3;
    #pragma unroll
    for (int m = 1; m < 64; m <<= 1) { s += __shfl_xor(s, m); sq += __shfl_xor(sq, m); }
    float mu = s * (1.0f / CC), var = sq * (1.0f / CC) - mu * mu;
    float rs = rsqrtf(var + 1e-5f);
    const float4 g4 = *reinterpret_cast<const float4*>(lng + l * 4);
    const float4 b4 = *reinterpret_cast<const float4*>(lnb + l * 4);
    float z0 = (v0 - mu) * rs * g4.x + b4.x;
    float z1 = (v1 - mu) * rs * g4.y + b4.y;
    float z2 = (v2 - mu) * rs * g4.z + b4.z;
    float z3 = (v3 - mu) * rs * g4.w + b4.w;
    ushort4 hs, ls;
    hs.x = f2b(z0); ls.x = f2b(z0 - bf2f(hs.x));
    hs.y = f2b(z1); ls.y = f2b(z1 - bf2f(hs.y));
    hs.z = f2b(z2); ls.z = f2b(z2 - bf2f(hs.z));
    hs.w = f2b(z3); ls.w = f2b(z3 - bf2f(hs.w));
    *reinterpret_cast<ushort4*>(zh + base + l * 4) = hs;
    *reinterpret_cast<ushort4*>(zl + base + l * 4) = ls;
}

// ---------------- rsa from bf16 qk buffer: rsa[r][h] = (q.k)/sqrt(32) ----------------
__global__ __launch_bounds__(256) void rsa2_k(const ushort_t* __restrict__ qk,
                                              float* __restrict__ rsa) {
    int row = blockIdx.x * 4 + (threadIdx.x >> 6);
    int l = threadIdx.x & 63;
    const ushort4 qa = *reinterpret_cast<const ushort4*>(qk + (size_t)row * 512 + l * 4);
    const ushort4 ka = *reinterpret_cast<const ushort4*>(qk + (size_t)row * 512 + 256 + l * 4);
    float p = bf2f(qa.x) * bf2f(ka.x) + bf2f(qa.y) * bf2f(ka.y)
            + bf2f(qa.z) * bf2f(ka.z) + bf2f(qa.w) * bf2f(ka.w);
    p += __shfl_xor(p, 1); p += __shfl_xor(p, 2); p += __shfl_xor(p, 4);
    if ((l & 7) == 0) rsa[(size_t)row * 8 + (l >> 3)] = p * 0.17677669529663689f;
}

// ---------------- cumsum pass 1: per-chunk totals of rsa*v (read-only) ----------------
__global__ __launch_bounds__(256) void cumsum1_k(const float* __restrict__ v,
                                                 const float* __restrict__ rsa,
                                                 float* __restrict__ tot) {
    int bi = blockIdx.x >> 3, ch = blockIdx.x & 7, c = threadIdx.x;
    int h = c >> 5;
    size_t row0 = (size_t)bi * BP1 + ch * 256;
    float s = 0.f;
    for (int j = 0; j < 256; ++j)
        s += v[(row0 + j) * CC + c] * rsa[(row0 + j) * 8 + h];
    tot[((size_t)bi * 8 + ch) * CC + c] = s;
}

// ---------------- cumsum pass 2: scan rsa*v + offset -> split planes ----------------
__global__ __launch_bounds__(256) void cumsum2_k(const float* __restrict__ v,
                                                 const float* __restrict__ rsa,
                                                 const float* __restrict__ tot,
                                                 ushort_t* __restrict__ ph,
                                                 ushort_t* __restrict__ pl) {
    int bi = blockIdx.x / 9, ch = blockIdx.x - bi * 9, c = threadIdx.x;
    int h = c >> 5;
    if (ch == 8) {   // row BB (untouched by cumsum): scale + split-pack
        size_t row = (size_t)bi * BP1 + BB;
        float val = v[row * CC + c] * rsa[row * 8 + h];
        ushort_t hh = f2b(val);
        ph[row * CC + c] = hh; pl[row * CC + c] = f2b(val - bf2f(hh));
        return;
    }
    float s = 0.f;
    for (int q = 0; q < ch; ++q) s += tot[((size_t)bi * 8 + q) * CC + c];
    size_t row0 = (size_t)bi * BP1 + ch * 256;
    for (int j = 0; j < 256; ++j) {
        size_t row = row0 + j;
        s += v[row * CC + c] * rsa[row * 8 + h];
        ushort_t hh = f2b(s);
        ph[row * CC + c] = hh;
        pl[row * CC + c] = f2b(s - bf2f(hh));
    }
}

// ---------------- split-bf16 MFMA GEMM, 4-wave 64x256 tile, fused-LN epilogue ----------------
// Out(MxN) = A(MxK) * W(NxK)^T ; grid = MT*NT (1-D), XCD-bijective swizzle.
// Each wave owns a 64x64 output slice (wc = wave id); tile spans full 256-col rows.
// F_LN: after writing Op (savespace), row LayerNorm -> z planes (zh=Op2, zlo optional).
template<int ALO>
__global__ __launch_bounds__(256) void mm_k(const ushort_t* __restrict__ Ah_g,
                                            const ushort_t* __restrict__ Al_g,
                                            const ushort_t* __restrict__ Bh_g,
                                            const ushort_t* __restrict__ Bl_g,
                                            void* __restrict__ Op,
                                            void* __restrict__ Op2,
                                            ushort_t* __restrict__ zlo,
                                            const float* __restrict__ bias,
                                            const float* __restrict__ lng,
                                            const float* __restrict__ lnb,
                                            int M, int K, int NC, int NT, int flags) {
    __shared__ __align__(16) short As_h[64 * 32];
    __shared__ __align__(16) short As_l[64 * 32];
    __shared__ __align__(16) short Bs_h[256 * 32];
    __shared__ __align__(16) short Bs_l[256 * 32];
    const int t = threadIdx.x;

    // XCD-bijective block swizzle (m204)
    const int nwg = gridDim.x;
    const int q8 = nwg >> 3, r8 = nwg & 7;
    const int xcd = blockIdx.x & 7, ii = blockIdx.x >> 3;
    const int wgid = (xcd < r8 ? xcd * (q8 + 1) : r8 * (q8 + 1) + (xcd - r8) * q8) + ii;
    const int nt_ = wgid % NT, mt = wgid / NT;
    const int n0 = nt_ * 256, m0 = mt * 64;

    const int wid = t >> 6, l = t & 63;
    const int wc = wid;                           // wave's 64-col slice

    // staging: A rows wid*16+(l>>2) (64 rows, 1 load/thread/plane);
    //          B chunks wid+4c, c=0..3 (256 rows, 4 loads/thread/plane)
    const int sc = (l & 3) * 8;
    int gaA = m0 + wid * 16 + (l >> 2); if (gaA >= M) gaA = M - 1;
    const ushort_t* pa  = Ah_g + (size_t)gaA * K + sc;
    const ushort_t* pal = ALO ? (Al_g + (size_t)gaA * K + sc) : nullptr;
    const ushort_t* pbh[4];
    const ushort_t* pbl[4];
    #pragma unroll
    for (int c = 0; c < 4; ++c) {
        int gb = n0 + (wid + 4 * c) * 16 + (l >> 2);
        pbh[c] = Bh_g + (size_t)gb * K + sc;
        pbl[c] = Bl_g + (size_t)gb * K + sc;
    }

    f32x4 acc[4][4];
    #pragma unroll
    for (int i = 0; i < 4; ++i)
        #pragma unroll
        for (int j = 0; j < 4; ++j) acc[i][j] = (f32x4)(0.0f);

    for (int k0 = 0; k0 < K; k0 += 32) {
        gload16(pa + k0, &As_h[wid * 512]);
        if (ALO) gload16(pal + k0, &As_l[wid * 512]);
        #pragma unroll
        for (int c = 0; c < 4; ++c) {
            gload16(pbh[c] + k0, &Bs_h[(wid + 4 * c) * 512]);
            gload16(pbl[c] + k0, &Bs_l[(wid + 4 * c) * 512]);
        }
        __syncthreads();
        short8 ah[4], al[4], bh[4], bl[4];
        #pragma unroll
        for (int i = 0; i < 4; ++i) {
            int ro = (i * 16 + (l & 15)) * 32 + (l >> 4) * 8;
            ah[i] = *reinterpret_cast<const short8*>(&As_h[ro]);
            if (ALO) al[i] = *reinterpret_cast<const short8*>(&As_l[ro]);
        }
        #pragma unroll
        for (int j = 0; j < 4; ++j) {
            int ro = (wc * 64 + j * 16 + (l & 15)) * 32 + (l >> 4) * 8;
            bh[j] = *reinterpret_cast<const short8*>(&Bs_h[ro]);
            bl[j] = *reinterpret_cast<const short8*>(&Bs_l[ro]);
        }
        #pragma unroll
        for (int i = 0; i < 4; ++i)
            #pragma unroll
            for (int j = 0; j < 4; ++j) {
                acc[i][j] = __builtin_amdgcn_mfma_f32_16x16x32_bf16(ah[i], bh[j], acc[i][j], 0, 0, 0);
                acc[i][j] = __builtin_amdgcn_mfma_f32_16x16x32_bf16(ah[i], bl[j], acc[i][j], 0, 0, 0);
                if (ALO)
                    acc[i][j] = __builtin_amdgcn_mfma_f32_16x16x32_bf16(al[i], bh[j], acc[i][j], 0, 0, 0);
            }
        __syncthreads();
    }

    // ---- epilogue pass 1: finalize v, write primary output, keep v in acc ----
    #pragma unroll
    for (int i = 0; i < 4; ++i)
        #pragma unroll
        for (int j = 0; j < 4; ++j) {
            int colb = n0 + wc * 64 + j * 16 + (l & 15);
            #pragma unroll
            for (int r = 0; r < 4; ++r) {
                int row = m0 + i * 16 + (l >> 4) * 4 + r;
                float v = acc[i][j][r];
                if (row >= M) { acc[i][j][r] = 0.0f; continue; }
                if (flags & F_QKV) {          // block-uniform by n-tile
                    if (colb < 512)
                        reinterpret_cast<ushort_t*>(Op)[(size_t)row * 512 + colb] = f2b(v);
                    else
                        reinterpret_cast<float*>(Op2)[(size_t)row * 256 + (colb - 512)] = v;
                    continue;
                }
                size_t g = (flags & F_ROWMAP) ? ((size_t)(row >> 11) * BP1 + 1 + (row & 2047))
                                             : (size_t)row;
                if (flags & F_BIAS1D) v += bias[colb];
                if (flags & F_BIAS2D) v += bias[g * (size_t)NC + colb];
                if (flags & F_GELU) {   // tanh-form GELU
                    float zt = v * (1.595769122f + 0.071354816f * v * v);
                    v = v / (1.0f + __expf(-zt));
                }
                size_t oi = g * (size_t)NC + colb;
                if (flags & F_OUTB16) {
                    reinterpret_cast<ushort_t*>(Op)[oi] = f2b(v);
                } else {
                    float* O = reinterpret_cast<float*>(Op);
                    if (flags & F_RESID) v += O[oi];
                    O[oi] = v;
                }
                acc[i][j][r] = v;
            }
        }

    // ---- epilogue pass 2: fused LayerNorm over full rows -> z planes ----
    if (flags & F_LN) {
        float2* lnred = reinterpret_cast<float2*>(As_h);   // [64][4], reuses dead A tile
        #pragma unroll
        for (int i = 0; i < 4; ++i)
            #pragma unroll
            for (int r = 0; r < 4; ++r) {
                float s  = acc[i][0][r] + acc[i][1][r] + acc[i][2][r] + acc[i][3][r];
                float sq = acc[i][0][r] * acc[i][0][r] + acc[i][1][r] * acc[i][1][r]
                         + acc[i][2][r] * acc[i][2][r] + acc[i][3][r] * acc[i][3][r];
                s += __shfl_xor(s, 1); sq += __shfl_xor(sq, 1);
                s += __shfl_xor(s, 2); sq += __shfl_xor(sq, 2);
                s += __shfl_xor(s, 4); sq += __shfl_xor(sq, 4);
                s += __shfl_xor(s, 8); sq += __shfl_xor(sq, 8);
                if ((l & 15) == 0) {
                    int lrow = i * 16 + (l >> 4) * 4 + r;   // 0..63
                    lnred[lrow * 4 + wc] = make_float2(s, sq);
                }
            }
        __syncthreads();
        ushort_t* zh_o = reinterpret_cast<ushort_t*>(Op2);
        #pragma unroll
        for (int i = 0; i < 4; ++i)
            #pragma unroll
            for (int r = 0; r < 4; ++r) {
                int lrow = i * 16 + (l >> 4) * 4 + r;
                int row = m0 + lrow;
                if (row >= M) continue;
                float2 t0 = lnred[lrow * 4 + 0], t1 = lnred[lrow * 4 + 1];
                float2 t2 = lnred[lrow * 4 + 2], t3 = lnred[lrow * 4 + 3];
                float s = t0.x + t1.x + t2.x + t3.x;
                float sq = t0.y + t1.y + t2.y + t3.y;
                float mu = s * (1.0f / CC), var = sq * (1.0f / CC) - mu * mu;
                float rs = rsqrtf(var + 1e-5f);
                size_t g = (flags & F_ROWMAP) ? ((size_t)(row >> 11) * BP1 + 1 + (row & 2047))
                                             : (size_t)row;
                #pragma unroll
                for (int j = 0; j < 4; ++j) {
                    int colb = wc * 64 + j * 16 + (l & 15);   // NC == 256 for LN kernels
                    float zv = (acc[i][j][r] - mu) * rs * lng[colb] + lnb[colb];
                    ushort_t hh = f2b(zv);
                    zh_o[g * 256 + colb] = hh;
                    if (zlo) zlo[g * 256 + colb] = f2b(zv - bf2f(hh));
                }
            }
    }
}

// ---------------- launch ----------------
extern "C" void kernel_launch(void* const* d_in, const int* in_sizes, int n_in,
                              void* d_out, int out_size, void* d_ws, size_t ws_size,
                              hipStream_t stream) {
    const float* x      = (const float*)d_in[0];
    const float* weight = (const float*)d_in[1];
    const float* bias   = (const float*)d_in[2];
    const float* cls    = (const float*)d_in[3];
    const float* Wqkv   = (const float*)d_in[4];
    const float* Wo     = (const float*)d_in[5];
    const float* ln1_g  = (const float*)d_in[6];
    const float* ln1_b  = (const float*)d_in[7];
    const float* ln2_g  = (const float*)d_in[8];
    const float* ln2_b  = (const float*)d_in[9];
    const float* fc1_w  = (const float*)d_in[10];
    const float* fc1_b  = (const float*)d_in[11];
    const float* fc2_w  = (const float*)d_in[12];
    const float* fc2_b  = (const float*)d_in[13];
    float* out = (float*)d_out;

    // ---- workspace (high-water 209,290,240 B — proven rounds 7-12) ----
    char* ws = (char*)d_ws;
    ushort_t* zh    = (ushort_t*)(ws + 0);
    ushort_t* zl    = (ushort_t*)(ws + 33570816);
    ushort_t* xh    = (ushort_t*)(ws + 67141632);
    ushort_t* xl    = (ushort_t*)(ws + 100712448);
    float*    vbuf  = (float*)(ws + 67141632);                 // overlays xh/xl (dead post-embed)
    ushort_t* qkbuf = (ushort_t*)(ws + 134283264);
    ushort_t* imh   = (ushort_t*)(ws + 134283264);             // overlays qkbuf
    ushort_t* iml   = (ushort_t*)(ws + 167854080);
    ushort_t* hbuf  = (ushort_t*)(ws + 67141632);              // spans R1+R2
    float*    rsa   = (float*)(ws + 201424896);
    float*    tot   = (float*)(ws + 203523072);
    ushort_t* wp    = (ushort_t*)(ws + 203785216);

    ushort_t* w_h    = wp;                 // weight  65,536
    ushort_t* w_l    = wp + 65536;
    ushort_t* wqkv_h = wp + 131072;        // Wqkv   589,824
    ushort_t* wqkv_l = wp + 720896;
    ushort_t* wo_h   = wp + 1310720;       // Wo     196,608
    ushort_t* wo_l   = wp + 1507328;
    ushort_t* fc1_h  = wp + 1703936;       // fc1    262,144
    ushort_t* fc1_l  = wp + 1966080;
    ushort_t* fc2_h  = wp + 2228224;       // fc2    262,144
    ushort_t* fc2_l  = wp + 2490368;       // end 2,752,512 -> 209,290,240 B

    pack2_k<<<256,  256, 0, stream>>>(weight, w_h,    w_l,    65536);
    pack2_k<<<2304, 256, 0, stream>>>(Wqkv,   wqkv_h, wqkv_l, 589824);
    pack2_k<<<768,  256, 0, stream>>>(Wo,     wo_h,   wo_l,   196608);
    pack2_k<<<1024, 256, 0, stream>>>(fc1_w,  fc1_h,  fc1_l,  262144);
    pack2_k<<<1024, 256, 0, stream>>>(fc2_w,  fc2_h,  fc2_l,  262144);
    pack2_k<<<65536, 256, 0, stream>>>(x, xh, xl, AA * BB * CC);

    // row 0 of each batch: cls + bias, LN1 -> z
    row0_k<<<AA, 64, 0, stream>>>(out, cls, bias, ln1_g, ln1_b, zh, zl);
    // embed + bias2d + fused LN1 -> savespace & z planes (M = 65536 -> 1024 m-tiles)
    mm_k<1><<<1024, 256, 0, stream>>>(xh, xl, w_h, w_l, out, zh, zl, bias, ln1_g, ln1_b,
                                      AA * BB, CC, CC, 1, F_ROWMAP | F_BIAS2D | F_LN);

    const int MT = (NROWS + 63) / 64;   // 1025
    for (int a = 0; a < NBLK; ++a) {
        const size_t aw = (size_t)a * 196608;   // per-layer Wqkv stride (3*8*32*256)
        // fused qkv: NC=768, q/k -> bf16 qkbuf, v -> fp32 vbuf
        mm_k<1><<<3 * MT, 256, 0, stream>>>(zh, zl, wqkv_h + aw, wqkv_l + aw,
                                            qkbuf, vbuf, nullptr, nullptr, nullptr, nullptr,
                                            NROWS, CC, 768, 3, F_QKV);
        rsa2_k<<<NROWS / 4, 256, 0, stream>>>(qkbuf, rsa);
        cumsum1_k<<<256, 256, 0, stream>>>(vbuf, rsa, tot);
        cumsum2_k<<<288, 256, 0, stream>>>(vbuf, rsa, tot, imh, iml);  // qkbuf dead
        // savespace += im @ Wo^T, fused LN2 -> zh (hi only; fc1 is 2-term)
        mm_k<1><<<MT, 256, 0, stream>>>(imh, iml, wo_h + (size_t)a * 65536,
                                        wo_l + (size_t)a * 65536, out, zh, nullptr,
                                        nullptr, ln2_g, ln2_b,
                                        NROWS, CC, CC, 1, F_RESID | F_LN);
        // h = gelu(z @ fc1^T + b) -> bf16 hbuf (A = zh single plane, 2-term)
        mm_k<0><<<4 * MT, 256, 0, stream>>>(zh, nullptr, fc1_h, fc1_l, hbuf, nullptr, nullptr,
                                            fc1_b, nullptr, nullptr,
                                            NROWS, CC, FFN, 4, F_BIAS1D | F_GELU | F_OUTB16);
        // savespace += h @ fc2^T + b, fused LN1 -> z (skip LN on last block)
        int f2f = F_BIAS1D | F_RESID | (a < NBLK - 1 ? F_LN : 0);
        mm_k<0><<<MT, 256, 0, stream>>>(hbuf, nullptr, fc2_h, fc2_l, out, zh, zl,
                                        fc2_b, ln1_g, ln1_b,
                                        NROWS, FFN, CC, 1, f2f);
    }
}

// Round 14
// 1900.751 us; speedup vs baseline: 1.4753x; 1.4753x over previous
//
#include <hip/hip_runtime.h>
#include <math.h>

#define AA 32
#define BB 2048
#define BP1 2049
#define CC 256
#define NROWS (AA * BP1)          // 65568
#define NBLK 3
#define FFN 1024

typedef unsigned int uint;
typedef unsigned short ushort_t;
typedef __attribute__((ext_vector_type(4))) float f32x4;
typedef __attribute__((ext_vector_type(8))) short short8;

// epilogue flag bits for mm_k (wave-uniform runtime flags)
#define F_ROWMAP 2
#define F_BIAS2D 4
#define F_BIAS1D 8
#define F_GELU   16
#define F_RESID  32
#define F_OUTB16 64
#define F_QKV    128

__device__ __forceinline__ float bf2f(ushort_t u) {
    return __uint_as_float(((uint)u) << 16);
}
__device__ __forceinline__ ushort_t f2b(float x) {   // fp32 -> bf16 RNE
    uint u = __float_as_uint(x);
    u += 0x7fff + ((u >> 16) & 1);
    return (ushort_t)(u >> 16);
}

// global -> LDS direct 16B load
typedef const uint __attribute__((address_space(1)))* gas_t;
typedef uint __attribute__((address_space(3)))* las_t;
__device__ __forceinline__ void gload16(const ushort_t* g, const short* l) {
    __builtin_amdgcn_global_load_lds(
        reinterpret_cast<gas_t>(reinterpret_cast<uintptr_t>(g)),
        reinterpret_cast<las_t>(static_cast<uint>(reinterpret_cast<uintptr_t>(l))),
        16, 0, 0);
}

// ---------------- fp32 -> bf16 planes (lo plane optional) ----------------
__global__ __launch_bounds__(256) void pack2_k(const float* __restrict__ src,
                                               ushort_t* __restrict__ dh,
                                               ushort_t* __restrict__ dl, int n) {
    int i = blockIdx.x * 256 + threadIdx.x;
    if (i < n) {
        float v = src[i];
        ushort_t h = f2b(v);
        dh[i] = h;
        if (dl) dl[i] = f2b(v - bf2f(h));
    }
}

// ---------------- row 0 of each batch: cls + bias ----------------
__global__ __launch_bounds__(256) void row0_k(float* __restrict__ out,
                                              const float* __restrict__ cls,
                                              const float* __restrict__ bias) {
    int i = blockIdx.x, t = threadIdx.x;
    size_t o = (size_t)i * BP1 * CC + t;
    out[o] = cls[i * CC + t] + bias[o];
}

// ---------------- layernorm f32 -> bf16 plane(s) (lo optional) ----------------
__global__ __launch_bounds__(256) void ln_k(const float* __restrict__ in,
                                            ushort_t* __restrict__ zh, ushort_t* __restrict__ zl,
                                            const float* __restrict__ g, const float* __restrict__ b) {
    int row = blockIdx.x * 4 + (threadIdx.x >> 6);
    int lane = threadIdx.x & 63;
    const float4 v = *reinterpret_cast<const float4*>(in + (size_t)row * CC + lane * 4);
    float s = v.x + v.y + v.z + v.w;
    float sq = v.x * v.x + v.y * v.y + v.z * v.z + v.w * v.w;
    #pragma unroll
    for (int m = 1; m < 64; m <<= 1) { s += __shfl_xor(s, m); sq += __shfl_xor(sq, m); }
    float mu = s * (1.0f / CC);
    float var = sq * (1.0f / CC) - mu * mu;
    float rs = rsqrtf(var + 1e-5f);
    const float4 gg = *reinterpret_cast<const float4*>(g + lane * 4);
    const float4 bb = *reinterpret_cast<const float4*>(b + lane * 4);
    float o[4];
    o[0] = (v.x - mu) * rs * gg.x + bb.x;
    o[1] = (v.y - mu) * rs * gg.y + bb.y;
    o[2] = (v.z - mu) * rs * gg.z + bb.z;
    o[3] = (v.w - mu) * rs * gg.w + bb.w;
    ushort4 hs;
    hs.x = f2b(o[0]); hs.y = f2b(o[1]); hs.z = f2b(o[2]); hs.w = f2b(o[3]);
    size_t base = (size_t)row * CC + lane * 4;
    *reinterpret_cast<ushort4*>(zh + base) = hs;
    if (zl) {
        ushort4 ls;
        ls.x = f2b(o[0] - bf2f(hs.x));
        ls.y = f2b(o[1] - bf2f(hs.y));
        ls.z = f2b(o[2] - bf2f(hs.z));
        ls.w = f2b(o[3] - bf2f(hs.w));
        *reinterpret_cast<ushort4*>(zl + base) = ls;
    }
}

// ---------------- rsa from bf16 qk buffer: rsa[r][h] = (q.k)/sqrt(32) ----------------
__global__ __launch_bounds__(256) void rsa2_k(const ushort_t* __restrict__ qk,
                                              float* __restrict__ rsa) {
    int row = blockIdx.x * 4 + (threadIdx.x >> 6);
    int l = threadIdx.x & 63;
    const ushort4 qa = *reinterpret_cast<const ushort4*>(qk + (size_t)row * 512 + l * 4);
    const ushort4 ka = *reinterpret_cast<const ushort4*>(qk + (size_t)row * 512 + 256 + l * 4);
    float p = bf2f(qa.x) * bf2f(ka.x) + bf2f(qa.y) * bf2f(ka.y)
            + bf2f(qa.z) * bf2f(ka.z) + bf2f(qa.w) * bf2f(ka.w);
    p += __shfl_xor(p, 1); p += __shfl_xor(p, 2); p += __shfl_xor(p, 4);
    if ((l & 7) == 0) rsa[(size_t)row * 8 + (l >> 3)] = p * 0.17677669529663689f;
}

// ---------------- cumsum pass 1: per-chunk totals of rsa*v (read-only) ----------------
__global__ __launch_bounds__(256) void cumsum1_k(const float* __restrict__ v,
                                                 const float* __restrict__ rsa,
                                                 float* __restrict__ tot) {
    int bi = blockIdx.x >> 3, ch = blockIdx.x & 7, c = threadIdx.x;
    int h = c >> 5;
    size_t row0 = (size_t)bi * BP1 + ch * 256;
    float s = 0.f;
    for (int j = 0; j < 256; ++j)
        s += v[(row0 + j) * CC + c] * rsa[(row0 + j) * 8 + h];
    tot[((size_t)bi * 8 + ch) * CC + c] = s;
}

// ---------------- cumsum pass 2: scan rsa*v + offset -> split planes ----------------
__global__ __launch_bounds__(256) void cumsum2_k(const float* __restrict__ v,
                                                 const float* __restrict__ rsa,
                                                 const float* __restrict__ tot,
                                                 ushort_t* __restrict__ ph,
                                                 ushort_t* __restrict__ pl) {
    int bi = blockIdx.x / 9, ch = blockIdx.x - bi * 9, c = threadIdx.x;
    int h = c >> 5;
    if (ch == 8) {   // row BB (untouched by cumsum): scale + split-pack
        size_t row = (size_t)bi * BP1 + BB;
        float val = v[row * CC + c] * rsa[row * 8 + h];
        ushort_t hh = f2b(val);
        ph[row * CC + c] = hh; pl[row * CC + c] = f2b(val - bf2f(hh));
        return;
    }
    float s = 0.f;
    for (int q = 0; q < ch; ++q) s += tot[((size_t)bi * 8 + q) * CC + c];
    size_t row0 = (size_t)bi * BP1 + ch * 256;
    for (int j = 0; j < 256; ++j) {
        size_t row = row0 + j;
        s += v[row * CC + c] * rsa[row * 8 + h];
        ushort_t hh = f2b(s);
        ph[row * CC + c] = hh;
        pl[row * CC + c] = f2b(s - bf2f(hh));
    }
}

// ---------------- split-bf16 MFMA GEMM (round-9 structure, proven best) ----------------
// Out(MxN) = A(MxK) * W(NxK)^T ; 1-D grid = NT*MT, XCD-bijective swizzle, n-fastest raster.
// ALO=1: A has hi+lo planes (3-term). ALO=0: A hi only (2-term, full-precision W).
template<int ALO>
__global__ __launch_bounds__(256) void mm_k(const ushort_t* __restrict__ Ah_g,
                                            const ushort_t* __restrict__ Al_g,
                                            const ushort_t* __restrict__ Bh_g,
                                            const ushort_t* __restrict__ Bl_g,
                                            void* __restrict__ Op,
                                            void* __restrict__ Op2,
                                            const float* __restrict__ bias,
                                            int M, int K, int NC, int NT, int flags) {
    __shared__ __align__(16) short As_h[4096];
    __shared__ __align__(16) short As_l[4096];
    __shared__ __align__(16) short Bs_h[4096];
    __shared__ __align__(16) short Bs_l[4096];
    const int t = threadIdx.x;

    // XCD-bijective block swizzle (m204)
    const int nwg = gridDim.x;
    const int q8 = nwg >> 3, r8 = nwg & 7;
    const int xcd = blockIdx.x & 7, ii = blockIdx.x >> 3;
    const int wgid = (xcd < r8 ? xcd * (q8 + 1) : r8 * (q8 + 1) + (xcd - r8) * q8) + ii;
    const int nt = wgid % NT, mt = wgid / NT;
    const int n0 = nt * 128, m0 = mt * 128;

    const int wid = t >> 6, l = t & 63;
    const int wr = wid >> 1, wc = wid & 1;

    // staging geometry: wave w covers 1KB chunks (w) and (w+4); lane l -> row l>>2, col (l&3)*8
    const int ch0 = wid, ch1 = wid + 4;
    const int sr0 = ch0 * 16 + (l >> 2);
    const int sr1 = ch1 * 16 + (l >> 2);
    const int sc  = (l & 3) * 8;
    int ga0 = m0 + sr0; if (ga0 >= M) ga0 = M - 1;
    int ga1 = m0 + sr1; if (ga1 >= M) ga1 = M - 1;
    const int gb0 = n0 + sr0, gb1 = n0 + sr1;

    f32x4 acc[4][4];
    #pragma unroll
    for (int i = 0; i < 4; ++i)
        #pragma unroll
        for (int j = 0; j < 4; ++j) acc[i][j] = (f32x4)(0.0f);

    for (int k0 = 0; k0 < K; k0 += 32) {
        gload16(Ah_g + (size_t)ga0 * K + k0 + sc, &As_h[ch0 * 512]);
        gload16(Ah_g + (size_t)ga1 * K + k0 + sc, &As_h[ch1 * 512]);
        if (ALO) {
            gload16(Al_g + (size_t)ga0 * K + k0 + sc, &As_l[ch0 * 512]);
            gload16(Al_g + (size_t)ga1 * K + k0 + sc, &As_l[ch1 * 512]);
        }
        gload16(Bh_g + (size_t)gb0 * K + k0 + sc, &Bs_h[ch0 * 512]);
        gload16(Bh_g + (size_t)gb1 * K + k0 + sc, &Bs_h[ch1 * 512]);
        gload16(Bl_g + (size_t)gb0 * K + k0 + sc, &Bs_l[ch0 * 512]);
        gload16(Bl_g + (size_t)gb1 * K + k0 + sc, &Bs_l[ch1 * 512]);
        __syncthreads();
        short8 ah[4], al[4], bh[4], bl[4];
        #pragma unroll
        for (int i = 0; i < 4; ++i) {
            int ro = (wr * 64 + i * 16 + (l & 15)) * 32 + (l >> 4) * 8;
            ah[i] = *reinterpret_cast<const short8*>(&As_h[ro]);
            if (ALO) al[i] = *reinterpret_cast<const short8*>(&As_l[ro]);
        }
        #pragma unroll
        for (int j = 0; j < 4; ++j) {
            int ro = (wc * 64 + j * 16 + (l & 15)) * 32 + (l >> 4) * 8;
            bh[j] = *reinterpret_cast<const short8*>(&Bs_h[ro]);
            bl[j] = *reinterpret_cast<const short8*>(&Bs_l[ro]);
        }
        #pragma unroll
        for (int i = 0; i < 4; ++i)
            #pragma unroll
            for (int j = 0; j < 4; ++j) {
                acc[i][j] = __builtin_amdgcn_mfma_f32_16x16x32_bf16(ah[i], bh[j], acc[i][j], 0, 0, 0);
                acc[i][j] = __builtin_amdgcn_mfma_f32_16x16x32_bf16(ah[i], bl[j], acc[i][j], 0, 0, 0);
                if (ALO)
                    acc[i][j] = __builtin_amdgcn_mfma_f32_16x16x32_bf16(al[i], bh[j], acc[i][j], 0, 0, 0);
            }
        __syncthreads();
    }

    // ---- epilogue ----
    #pragma unroll
    for (int i = 0; i < 4; ++i)
        #pragma unroll
        for (int j = 0; j < 4; ++j) {
            int colb = n0 + wc * 64 + j * 16 + (l & 15);
            #pragma unroll
            for (int r = 0; r < 4; ++r) {
                int row = m0 + wr * 64 + i * 16 + (l >> 4) * 4 + r;
                if (row >= M) continue;
                float v = acc[i][j][r];
                if (flags & F_QKV) {          // block-uniform by n-tile
                    if (colb < 512)
                        reinterpret_cast<ushort_t*>(Op)[(size_t)row * 512 + colb] = f2b(v);
                    else
                        reinterpret_cast<float*>(Op2)[(size_t)row * 256 + (colb - 512)] = v;
                    continue;
                }
                size_t g = (flags & F_ROWMAP) ? ((size_t)(row >> 11) * BP1 + 1 + (row & 2047))
                                             : (size_t)row;
                if (flags & F_BIAS1D) v += bias[colb];
                if (flags & F_BIAS2D) v += bias[g * (size_t)NC + colb];
                if (flags & F_GELU) {   // tanh-form GELU: v * sigmoid(1.5958v + 0.07135v^3)
                    float z = v * (1.595769122f + 0.071354816f * v * v);
                    v = v / (1.0f + __expf(-z));
                }
                size_t oi = g * (size_t)NC + colb;
                if (flags & F_OUTB16) {
                    reinterpret_cast<ushort_t*>(Op)[oi] = f2b(v);
                } else {
                    float* O = reinterpret_cast<float*>(Op);
                    if (flags & F_RESID) v += O[oi];
                    O[oi] = v;
                }
            }
        }
}

// ---------------- launch ----------------
extern "C" void kernel_launch(void* const* d_in, const int* in_sizes, int n_in,
                              void* d_out, int out_size, void* d_ws, size_t ws_size,
                              hipStream_t stream) {
    const float* x      = (const float*)d_in[0];
    const float* weight = (const float*)d_in[1];
    const float* bias   = (const float*)d_in[2];
    const float* cls    = (const float*)d_in[3];
    const float* Wqkv   = (const float*)d_in[4];
    const float* Wo     = (const float*)d_in[5];
    const float* ln1_g  = (const float*)d_in[6];
    const float* ln1_b  = (const float*)d_in[7];
    const float* ln2_g  = (const float*)d_in[8];
    const float* ln2_b  = (const float*)d_in[9];
    const float* fc1_w  = (const float*)d_in[10];
    const float* fc1_b  = (const float*)d_in[11];
    const float* fc2_w  = (const float*)d_in[12];
    const float* fc2_b  = (const float*)d_in[13];
    float* out = (float*)d_out;

    // ---- workspace (high-water 209,290,240 B — proven rounds 7-13) ----
    // zh  [0,          33,570,816)   z hi plane (x hi pre-embed)
    // zl  [33,570,816, 67,141,632)   (dead this round — no lo-z consumer)
    // R1  [67,141,632,134,283,264)   vbuf f32 -> hbuf lower half
    // R2  [134,283,264,201,424,896)  qkbuf bf16 -> imh+iml planes -> hbuf upper half
    // rsa [201,424,896,203,523,072)
    // tot [203,523,072,203,785,216)
    // wp  [203,785,216,209,290,240)  weight planes (hi|lo per weight)
    char* ws = (char*)d_ws;
    ushort_t* zh    = (ushort_t*)(ws + 0);
    float*    vbuf  = (float*)(ws + 67141632);
    ushort_t* qkbuf = (ushort_t*)(ws + 134283264);
    ushort_t* imh   = (ushort_t*)(ws + 134283264);             // overlays qkbuf
    ushort_t* iml   = (ushort_t*)(ws + 167854080);
    ushort_t* hbuf  = (ushort_t*)(ws + 67141632);              // spans R1+R2
    float*    rsa   = (float*)(ws + 201424896);
    float*    tot   = (float*)(ws + 203523072);
    ushort_t* wp    = (ushort_t*)(ws + 203785216);

    ushort_t* w_h    = wp;                 // weight  65,536
    ushort_t* w_l    = wp + 65536;
    ushort_t* wqkv_h = wp + 131072;        // Wqkv   589,824
    ushort_t* wqkv_l = wp + 720896;
    ushort_t* wo_h   = wp + 1310720;       // Wo     196,608
    ushort_t* wo_l   = wp + 1507328;
    ushort_t* fc1_h  = wp + 1703936;       // fc1    262,144
    ushort_t* fc1_l  = wp + 1966080;
    ushort_t* fc2_h  = wp + 2228224;       // fc2    262,144
    ushort_t* fc2_l  = wp + 2490368;       // end 2,752,512 -> 209,290,240 B

    pack2_k<<<256,  256, 0, stream>>>(weight, w_h,    w_l,    65536);
    pack2_k<<<2304, 256, 0, stream>>>(Wqkv,   wqkv_h, wqkv_l, 589824);
    pack2_k<<<768,  256, 0, stream>>>(Wo,     wo_h,   wo_l,   196608);
    pack2_k<<<1024, 256, 0, stream>>>(fc1_w,  fc1_h,  fc1_l,  262144);
    pack2_k<<<1024, 256, 0, stream>>>(fc2_w,  fc2_h,  fc2_l,  262144);
    // pack x hi-only into zh (consumed by embed GEMM, then ln_k overwrites)
    pack2_k<<<65536, 256, 0, stream>>>(x, zh, nullptr, AA * BB * CC);

    row0_k<<<AA, 256, 0, stream>>>(out, cls, bias);
    // embed: out[i,1+j,:] = x[i,j,:] @ weight^T + bias  (2-term: x hi only)
    mm_k<0><<<1024, 256, 0, stream>>>(zh, nullptr, w_h, w_l, out, nullptr, bias,
                                      AA * BB, CC, CC, 2, F_ROWMAP | F_BIAS2D);

    const int MT = (NROWS + 127) / 128;   // 513
    for (int a = 0; a < NBLK; ++a) {
        const size_t aw = (size_t)a * 196608;   // per-layer Wqkv stride (3*8*32*256)
        ln_k<<<NROWS / 4, 256, 0, stream>>>(out, zh, nullptr, ln1_g, ln1_b);
        // fused qkv: NC=768, q/k -> bf16 qkbuf, v -> fp32 vbuf  (2-term: z hi only)
        mm_k<0><<<6 * MT, 256, 0, stream>>>(zh, nullptr, wqkv_h + aw, wqkv_l + aw,
                                            qkbuf, vbuf, nullptr,
                                            NROWS, CC, 768, 6, F_QKV);
        rsa2_k<<<NROWS / 4, 256, 0, stream>>>(qkbuf, rsa);
        cumsum1_k<<<256, 256, 0, stream>>>(vbuf, rsa, tot);
        cumsum2_k<<<288, 256, 0, stream>>>(vbuf, rsa, tot, imh, iml);  // qkbuf dead
        // savespace += im @ Wo^T  (3-term: im is the large-magnitude cumsum tensor)
        mm_k<1><<<2 * MT, 256, 0, stream>>>(imh, iml, wo_h + (size_t)a * 65536,
                                            wo_l + (size_t)a * 65536, out, nullptr, nullptr,
                                            NROWS, CC, CC, 2, F_RESID);
        ln_k<<<NROWS / 4, 256, 0, stream>>>(out, zh, nullptr, ln2_g, ln2_b);
        // h = gelu(z @ fc1^T + b) -> bf16 hbuf  (2-term, validated r12/r13)
        mm_k<0><<<8 * MT, 256, 0, stream>>>(zh, nullptr, fc1_h, fc1_l, hbuf, nullptr, fc1_b,
                                            NROWS, CC, FFN, 8, F_BIAS1D | F_GELU | F_OUTB16);
        // savespace += h @ fc2^T + b  (2-term: h single plane)
        mm_k<0><<<2 * MT, 256, 0, stream>>>(hbuf, nullptr, fc2_h, fc2_l, out, nullptr, fc2_b,
                                            NROWS, FFN, CC, 2, F_BIAS1D | F_RESID);
    }
}

// Round 15
// 1786.130 us; speedup vs baseline: 1.5700x; 1.0642x over previous
//
#include <hip/hip_runtime.h>
#include <math.h>

#define AA 32
#define BB 2048
#define BP1 2049
#define CC 256
#define NROWS (AA * BP1)          // 65568
#define NBLK 3
#define FFN 1024

typedef unsigned int uint;
typedef unsigned short ushort_t;
typedef __attribute__((ext_vector_type(4))) float f32x4;
typedef __attribute__((ext_vector_type(8))) short short8;

// epilogue flag bits for mm_k (wave-uniform runtime flags)
#define F_ROWMAP 2
#define F_BIAS2D 4
#define F_BIAS1D 8
#define F_GELU   16
#define F_RESID  32
#define F_OUTB16 64
#define F_QKV    128

__device__ __forceinline__ float bf2f(ushort_t u) {
    return __uint_as_float(((uint)u) << 16);
}
__device__ __forceinline__ ushort_t f2b(float x) {   // fp32 -> bf16 RNE
    uint u = __float_as_uint(x);
    u += 0x7fff + ((u >> 16) & 1);
    return (ushort_t)(u >> 16);
}

// global -> LDS direct 16B load
typedef const uint __attribute__((address_space(1)))* gas_t;
typedef uint __attribute__((address_space(3)))* las_t;
__device__ __forceinline__ void gload16(const ushort_t* g, const short* l) {
    __builtin_amdgcn_global_load_lds(
        reinterpret_cast<gas_t>(reinterpret_cast<uintptr_t>(g)),
        reinterpret_cast<las_t>(static_cast<uint>(reinterpret_cast<uintptr_t>(l))),
        16, 0, 0);
}

// ---------------- fp32 -> bf16 planes (lo plane optional) ----------------
__global__ __launch_bounds__(256) void pack2_k(const float* __restrict__ src,
                                               ushort_t* __restrict__ dh,
                                               ushort_t* __restrict__ dl, int n) {
    int i = blockIdx.x * 256 + threadIdx.x;
    if (i < n) {
        float v = src[i];
        ushort_t h = f2b(v);
        dh[i] = h;
        if (dl) dl[i] = f2b(v - bf2f(h));
    }
}

// ---------------- Wqkv pack with head-interleaved q/k rows ----------------
// dst row order per layer: [h0q(32) h0k(32) h1q(32) h1k(32) ... h7q h7k, v(256)]
// src layout per layer (3,8,32,256): row = x*256 + h*32 + d
__global__ __launch_bounds__(256) void wqkv_pack_k(const float* __restrict__ src,
                                                   ushort_t* __restrict__ dh,
                                                   ushort_t* __restrict__ dl) {
    int i = blockIdx.x * 256 + threadIdx.x;      // 589,824 total
    if (i >= 589824) return;
    int c = i & 255;
    int rr = (i >> 8) % 768;
    int a = i / (768 * 256);
    int srcrow;
    if (rr < 512) {
        int head = rr >> 6, half = (rr >> 5) & 1, d = rr & 31;
        srcrow = half * 256 + head * 32 + d;
    } else {
        srcrow = rr;                              // v rows already at 512..767
    }
    float v = src[((size_t)a * 768 + srcrow) * 256 + c];
    ushort_t h = f2b(v);
    dh[i] = h;
    dl[i] = f2b(v - bf2f(h));
}

// ---------------- row 0 of each batch: cls + bias ----------------
__global__ __launch_bounds__(256) void row0_k(float* __restrict__ out,
                                              const float* __restrict__ cls,
                                              const float* __restrict__ bias) {
    int i = blockIdx.x, t = threadIdx.x;
    size_t o = (size_t)i * BP1 * CC + t;
    out[o] = cls[i * CC + t] + bias[o];
}

// ---------------- layernorm f32 -> bf16 plane(s) (lo optional) ----------------
__global__ __launch_bounds__(256) void ln_k(const float* __restrict__ in,
                                            ushort_t* __restrict__ zh, ushort_t* __restrict__ zl,
                                            const float* __restrict__ g, const float* __restrict__ b) {
    int row = blockIdx.x * 4 + (threadIdx.x >> 6);
    int lane = threadIdx.x & 63;
    const float4 v = *reinterpret_cast<const float4*>(in + (size_t)row * CC + lane * 4);
    float s = v.x + v.y + v.z + v.w;
    float sq = v.x * v.x + v.y * v.y + v.z * v.z + v.w * v.w;
    #pragma unroll
    for (int m = 1; m < 64; m <<= 1) { s += __shfl_xor(s, m); sq += __shfl_xor(sq, m); }
    float mu = s * (1.0f / CC);
    float var = sq * (1.0f / CC) - mu * mu;
    float rs = rsqrtf(var + 1e-5f);
    const float4 gg = *reinterpret_cast<const float4*>(g + lane * 4);
    const float4 bb = *reinterpret_cast<const float4*>(b + lane * 4);
    float o[4];
    o[0] = (v.x - mu) * rs * gg.x + bb.x;
    o[1] = (v.y - mu) * rs * gg.y + bb.y;
    o[2] = (v.z - mu) * rs * gg.z + bb.z;
    o[3] = (v.w - mu) * rs * gg.w + bb.w;
    ushort4 hs;
    hs.x = f2b(o[0]); hs.y = f2b(o[1]); hs.z = f2b(o[2]); hs.w = f2b(o[3]);
    size_t base = (size_t)row * CC + lane * 4;
    *reinterpret_cast<ushort4*>(zh + base) = hs;
    if (zl) {
        ushort4 ls;
        ls.x = f2b(o[0] - bf2f(hs.x));
        ls.y = f2b(o[1] - bf2f(hs.y));
        ls.z = f2b(o[2] - bf2f(hs.z));
        ls.w = f2b(o[3] - bf2f(hs.w));
        *reinterpret_cast<ushort4*>(zl + base) = ls;
    }
}

// ---------------- cumsum pass 1: per-chunk totals of rsa*v (read-only) ----------------
__global__ __launch_bounds__(256) void cumsum1_k(const float* __restrict__ v,
                                                 const float* __restrict__ rsa,
                                                 float* __restrict__ tot) {
    int bi = blockIdx.x >> 3, ch = blockIdx.x & 7, c = threadIdx.x;
    int h = c >> 5;
    size_t row0 = (size_t)bi * BP1 + ch * 256;
    float s = 0.f;
    for (int j = 0; j < 256; ++j)
        s += v[(row0 + j) * CC + c] * rsa[(row0 + j) * 8 + h];
    tot[((size_t)bi * 8 + ch) * CC + c] = s;
}

// ---------------- cumsum pass 2: scan rsa*v + offset -> split planes ----------------
__global__ __launch_bounds__(256) void cumsum2_k(const float* __restrict__ v,
                                                 const float* __restrict__ rsa,
                                                 const float* __restrict__ tot,
                                                 ushort_t* __restrict__ ph,
                                                 ushort_t* __restrict__ pl) {
    int bi = blockIdx.x / 9, ch = blockIdx.x - bi * 9, c = threadIdx.x;
    int h = c >> 5;
    if (ch == 8) {   // row BB (untouched by cumsum): scale + split-pack
        size_t row = (size_t)bi * BP1 + BB;
        float val = v[row * CC + c] * rsa[row * 8 + h];
        ushort_t hh = f2b(val);
        ph[row * CC + c] = hh; pl[row * CC + c] = f2b(val - bf2f(hh));
        return;
    }
    float s = 0.f;
    for (int q = 0; q < ch; ++q) s += tot[((size_t)bi * 8 + q) * CC + c];
    size_t row0 = (size_t)bi * BP1 + ch * 256;
    for (int j = 0; j < 256; ++j) {
        size_t row = row0 + j;
        s += v[row * CC + c] * rsa[row * 8 + h];
        ushort_t hh = f2b(s);
        ph[row * CC + c] = hh;
        pl[row * CC + c] = f2b(s - bf2f(hh));
    }
}

// ---------------- split-bf16 MFMA GEMM (round-9 structure, proven best) ----------------
// Out(MxN) = A(MxK) * W(NxK)^T ; 1-D grid = NT*MT, XCD-bijective swizzle, n-fastest raster.
// ALO=1: A has hi+lo planes (3-term). ALO=0: A hi only (2-term, full-precision W).
// F_QKV (head-interleaved W): qk tiles (cols<512) -> in-register rsa (Op, fp32);
//                             v tiles -> fp32 vbuf (Op2).
template<int ALO>
__global__ __launch_bounds__(256) void mm_k(const ushort_t* __restrict__ Ah_g,
                                            const ushort_t* __restrict__ Al_g,
                                            const ushort_t* __restrict__ Bh_g,
                                            const ushort_t* __restrict__ Bl_g,
                                            void* __restrict__ Op,
                                            void* __restrict__ Op2,
                                            const float* __restrict__ bias,
                                            int M, int K, int NC, int NT, int flags) {
    __shared__ __align__(16) short As_h[4096];
    __shared__ __align__(16) short As_l[4096];
    __shared__ __align__(16) short Bs_h[4096];
    __shared__ __align__(16) short Bs_l[4096];
    const int t = threadIdx.x;

    // XCD-bijective block swizzle (m204)
    const int nwg = gridDim.x;
    const int q8 = nwg >> 3, r8 = nwg & 7;
    const int xcd = blockIdx.x & 7, ii = blockIdx.x >> 3;
    const int wgid = (xcd < r8 ? xcd * (q8 + 1) : r8 * (q8 + 1) + (xcd - r8) * q8) + ii;
    const int nt = wgid % NT, mt = wgid / NT;
    const int n0 = nt * 128, m0 = mt * 128;

    const int wid = t >> 6, l = t & 63;
    const int wr = wid >> 1, wc = wid & 1;

    // staging geometry: wave w covers 1KB chunks (w) and (w+4); lane l -> row l>>2, col (l&3)*8
    const int ch0 = wid, ch1 = wid + 4;
    const int sr0 = ch0 * 16 + (l >> 2);
    const int sr1 = ch1 * 16 + (l >> 2);
    const int sc  = (l & 3) * 8;
    int ga0 = m0 + sr0; if (ga0 >= M) ga0 = M - 1;
    int ga1 = m0 + sr1; if (ga1 >= M) ga1 = M - 1;
    const int gb0 = n0 + sr0, gb1 = n0 + sr1;

    f32x4 acc[4][4];
    #pragma unroll
    for (int i = 0; i < 4; ++i)
        #pragma unroll
        for (int j = 0; j < 4; ++j) acc[i][j] = (f32x4)(0.0f);

    for (int k0 = 0; k0 < K; k0 += 32) {
        gload16(Ah_g + (size_t)ga0 * K + k0 + sc, &As_h[ch0 * 512]);
        gload16(Ah_g + (size_t)ga1 * K + k0 + sc, &As_h[ch1 * 512]);
        if (ALO) {
            gload16(Al_g + (size_t)ga0 * K + k0 + sc, &As_l[ch0 * 512]);
            gload16(Al_g + (size_t)ga1 * K + k0 + sc, &As_l[ch1 * 512]);
        }
        gload16(Bh_g + (size_t)gb0 * K + k0 + sc, &Bs_h[ch0 * 512]);
        gload16(Bh_g + (size_t)gb1 * K + k0 + sc, &Bs_h[ch1 * 512]);
        gload16(Bl_g + (size_t)gb0 * K + k0 + sc, &Bs_l[ch0 * 512]);
        gload16(Bl_g + (size_t)gb1 * K + k0 + sc, &Bs_l[ch1 * 512]);
        __syncthreads();
        short8 ah[4], al[4], bh[4], bl[4];
        #pragma unroll
        for (int i = 0; i < 4; ++i) {
            int ro = (wr * 64 + i * 16 + (l & 15)) * 32 + (l >> 4) * 8;
            ah[i] = *reinterpret_cast<const short8*>(&As_h[ro]);
            if (ALO) al[i] = *reinterpret_cast<const short8*>(&As_l[ro]);
        }
        #pragma unroll
        for (int j = 0; j < 4; ++j) {
            int ro = (wc * 64 + j * 16 + (l & 15)) * 32 + (l >> 4) * 8;
            bh[j] = *reinterpret_cast<const short8*>(&Bs_h[ro]);
            bl[j] = *reinterpret_cast<const short8*>(&Bs_l[ro]);
        }
        #pragma unroll
        for (int i = 0; i < 4; ++i)
            #pragma unroll
            for (int j = 0; j < 4; ++j) {
                acc[i][j] = __builtin_amdgcn_mfma_f32_16x16x32_bf16(ah[i], bh[j], acc[i][j], 0, 0, 0);
                acc[i][j] = __builtin_amdgcn_mfma_f32_16x16x32_bf16(ah[i], bl[j], acc[i][j], 0, 0, 0);
                if (ALO)
                    acc[i][j] = __builtin_amdgcn_mfma_f32_16x16x32_bf16(al[i], bh[j], acc[i][j], 0, 0, 0);
            }
        __syncthreads();
    }

    // ---- F_QKV epilogue: fused rsa (qk tiles) / vbuf store (v tiles) ----
    if (flags & F_QKV) {
        const int cb0 = n0 + wc * 64;             // wave-uniform
        if (cb0 < 512) {                          // head-interleaved q/k tile
            float* rsaO = reinterpret_cast<float*>(Op);
            const int head = cb0 >> 6;            // 64 cols per head: q(32)|k(32)
            #pragma unroll
            for (int i = 0; i < 4; ++i)
                #pragma unroll
                for (int r = 0; r < 4; ++r) {
                    // q d=(j*16+(l&15)) for j=0,1 ; k same d at j=2,3
                    float p = acc[i][0][r] * acc[i][2][r] + acc[i][1][r] * acc[i][3][r];
                    p += __shfl_xor(p, 1); p += __shfl_xor(p, 2);
                    p += __shfl_xor(p, 4); p += __shfl_xor(p, 8);
                    int row = m0 + wr * 64 + i * 16 + (l >> 4) * 4 + r;
                    if ((l & 15) == 0 && row < M)
                        rsaO[(size_t)row * 8 + head] = p * 0.17677669529663689f;
                }
        } else {                                  // v tile -> fp32 vbuf
            float* vO = reinterpret_cast<float*>(Op2);
            #pragma unroll
            for (int i = 0; i < 4; ++i)
                #pragma unroll
                for (int j = 0; j < 4; ++j) {
                    int colb = cb0 + j * 16 + (l & 15) - 512;
                    #pragma unroll
                    for (int r = 0; r < 4; ++r) {
                        int row = m0 + wr * 64 + i * 16 + (l >> 4) * 4 + r;
                        if (row < M) vO[(size_t)row * 256 + colb] = acc[i][j][r];
                    }
                }
        }
        return;
    }

    // ---- general epilogue ----
    #pragma unroll
    for (int i = 0; i < 4; ++i)
        #pragma unroll
        for (int j = 0; j < 4; ++j) {
            int colb = n0 + wc * 64 + j * 16 + (l & 15);
            #pragma unroll
            for (int r = 0; r < 4; ++r) {
                int row = m0 + wr * 64 + i * 16 + (l >> 4) * 4 + r;
                if (row >= M) continue;
                float v = acc[i][j][r];
                size_t g = (flags & F_ROWMAP) ? ((size_t)(row >> 11) * BP1 + 1 + (row & 2047))
                                             : (size_t)row;
                if (flags & F_BIAS1D) v += bias[colb];
                if (flags & F_BIAS2D) v += bias[g * (size_t)NC + colb];
                if (flags & F_GELU) {   // tanh-form GELU: v * sigmoid(1.5958v + 0.07135v^3)
                    float z = v * (1.595769122f + 0.071354816f * v * v);
                    v = v / (1.0f + __expf(-z));
                }
                size_t oi = g * (size_t)NC + colb;
                if (flags & F_OUTB16) {
                    reinterpret_cast<ushort_t*>(Op)[oi] = f2b(v);
                } else {
                    float* O = reinterpret_cast<float*>(Op);
                    if (flags & F_RESID) v += O[oi];
                    O[oi] = v;
                }
            }
        }
}

// ---------------- launch ----------------
extern "C" void kernel_launch(void* const* d_in, const int* in_sizes, int n_in,
                              void* d_out, int out_size, void* d_ws, size_t ws_size,
                              hipStream_t stream) {
    const float* x      = (const float*)d_in[0];
    const float* weight = (const float*)d_in[1];
    const float* bias   = (const float*)d_in[2];
    const float* cls    = (const float*)d_in[3];
    const float* Wqkv   = (const float*)d_in[4];
    const float* Wo     = (const float*)d_in[5];
    const float* ln1_g  = (const float*)d_in[6];
    const float* ln1_b  = (const float*)d_in[7];
    const float* ln2_g  = (const float*)d_in[8];
    const float* ln2_b  = (const float*)d_in[9];
    const float* fc1_w  = (const float*)d_in[10];
    const float* fc1_b  = (const float*)d_in[11];
    const float* fc2_w  = (const float*)d_in[12];
    const float* fc2_b  = (const float*)d_in[13];
    float* out = (float*)d_out;

    // ---- workspace (high-water 209,290,240 B — proven rounds 7-14) ----
    // zh  [0,          33,570,816)   z hi plane (x hi pre-embed)
    // R1  [67,141,632,134,283,264)   vbuf f32 -> hbuf lower half
    // R2  [134,283,264,201,424,896)  imh+iml planes -> hbuf upper half
    // rsa [201,424,896,203,523,072)
    // tot [203,523,072,203,785,216)
    // wp  [203,785,216,209,290,240)  weight planes (hi|lo per weight)
    char* ws = (char*)d_ws;
    ushort_t* zh    = (ushort_t*)(ws + 0);
    float*    vbuf  = (float*)(ws + 67141632);
    ushort_t* imh   = (ushort_t*)(ws + 134283264);
    ushort_t* iml   = (ushort_t*)(ws + 167854080);
    ushort_t* hbuf  = (ushort_t*)(ws + 67141632);              // spans R1+R2
    float*    rsa   = (float*)(ws + 201424896);
    float*    tot   = (float*)(ws + 203523072);
    ushort_t* wp    = (ushort_t*)(ws + 203785216);

    ushort_t* w_h    = wp;                 // weight  65,536
    ushort_t* w_l    = wp + 65536;
    ushort_t* wqkv_h = wp + 131072;        // Wqkv   589,824 (head-interleaved)
    ushort_t* wqkv_l = wp + 720896;
    ushort_t* wo_h   = wp + 1310720;       // Wo     196,608
    ushort_t* wo_l   = wp + 1507328;
    ushort_t* fc1_h  = wp + 1703936;       // fc1    262,144
    ushort_t* fc1_l  = wp + 1966080;
    ushort_t* fc2_h  = wp + 2228224;       // fc2    262,144
    ushort_t* fc2_l  = wp + 2490368;       // end 2,752,512 -> 209,290,240 B

    pack2_k<<<256,  256, 0, stream>>>(weight, w_h,    w_l,    65536);
    wqkv_pack_k<<<2304, 256, 0, stream>>>(Wqkv, wqkv_h, wqkv_l);
    pack2_k<<<768,  256, 0, stream>>>(Wo,     wo_h,   wo_l,   196608);
    pack2_k<<<1024, 256, 0, stream>>>(fc1_w,  fc1_h,  fc1_l,  262144);
    pack2_k<<<1024, 256, 0, stream>>>(fc2_w,  fc2_h,  fc2_l,  262144);
    // pack x hi-only into zh (consumed by embed GEMM, then ln_k overwrites)
    pack2_k<<<65536, 256, 0, stream>>>(x, zh, nullptr, AA * BB * CC);

    row0_k<<<AA, 256, 0, stream>>>(out, cls, bias);
    // embed: out[i,1+j,:] = x[i,j,:] @ weight^T + bias  (2-term: x hi only)
    mm_k<0><<<1024, 256, 0, stream>>>(zh, nullptr, w_h, w_l, out, nullptr, bias,
                                      AA * BB, CC, CC, 2, F_ROWMAP | F_BIAS2D);

    const int MT = (NROWS + 127) / 128;   // 513
    for (int a = 0; a < NBLK; ++a) {
        const size_t aw = (size_t)a * 196608;   // per-layer Wqkv stride
        ln_k<<<NROWS / 4, 256, 0, stream>>>(out, zh, nullptr, ln1_g, ln1_b);
        // fused qkv: qk tiles -> rsa in-register (fp32), v tiles -> vbuf
        mm_k<0><<<6 * MT, 256, 0, stream>>>(zh, nullptr, wqkv_h + aw, wqkv_l + aw,
                                            rsa, vbuf, nullptr,
                                            NROWS, CC, 768, 6, F_QKV);
        cumsum1_k<<<256, 256, 0, stream>>>(vbuf, rsa, tot);
        cumsum2_k<<<288, 256, 0, stream>>>(vbuf, rsa, tot, imh, iml);
        // savespace += im @ Wo^T  (3-term: im is the large-magnitude cumsum tensor)
        mm_k<1><<<2 * MT, 256, 0, stream>>>(imh, iml, wo_h + (size_t)a * 65536,
                                            wo_l + (size_t)a * 65536, out, nullptr, nullptr,
                                            NROWS, CC, CC, 2, F_RESID);
        ln_k<<<NROWS / 4, 256, 0, stream>>>(out, zh, nullptr, ln2_g, ln2_b);
        // h = gelu(z @ fc1^T + b) -> bf16 hbuf  (2-term)
        mm_k<0><<<8 * MT, 256, 0, stream>>>(zh, nullptr, fc1_h, fc1_l, hbuf, nullptr, fc1_b,
                                            NROWS, CC, FFN, 8, F_BIAS1D | F_GELU | F_OUTB16);
        // savespace += h @ fc2^T + b  (2-term: h single plane)
        mm_k<0><<<2 * MT, 256, 0, stream>>>(hbuf, nullptr, fc2_h, fc2_l, out, nullptr, fc2_b,
                                            NROWS, FFN, CC, 2, F_BIAS1D | F_RESID);
    }
}

// Round 16
// 1704.602 us; speedup vs baseline: 1.6450x; 1.0478x over previous
//
#include <hip/hip_runtime.h>
#include <math.h>

#define AA 32
#define BB 2048
#define BP1 2049
#define CC 256
#define NROWS (AA * BP1)          // 65568
#define NBLK 3
#define FFN 1024

typedef unsigned int uint;
typedef unsigned short ushort_t;
typedef __attribute__((ext_vector_type(4))) float f32x4;
typedef __attribute__((ext_vector_type(8))) short short8;

// epilogue flag bits for mm_k (wave-uniform runtime flags)
#define F_ROWMAP 2
#define F_BIAS2D 4
#define F_BIAS1D 8
#define F_GELU   16
#define F_RESID  32
#define F_OUTB16 64
#define F_QKV    128

__device__ __forceinline__ float bf2f(ushort_t u) {
    return __uint_as_float(((uint)u) << 16);
}
__device__ __forceinline__ ushort_t f2b(float x) {   // fp32 -> bf16 RNE
    uint u = __float_as_uint(x);
    u += 0x7fff + ((u >> 16) & 1);
    return (ushort_t)(u >> 16);
}

// global -> LDS direct 16B load
typedef const uint __attribute__((address_space(1)))* gas_t;
typedef uint __attribute__((address_space(3)))* las_t;
__device__ __forceinline__ void gload16(const ushort_t* g, const short* l) {
    __builtin_amdgcn_global_load_lds(
        reinterpret_cast<gas_t>(reinterpret_cast<uintptr_t>(g)),
        reinterpret_cast<las_t>(static_cast<uint>(reinterpret_cast<uintptr_t>(l))),
        16, 0, 0);
}

// ---------------- fp32 -> bf16 planes (lo plane optional) ----------------
__global__ __launch_bounds__(256) void pack2_k(const float* __restrict__ src,
                                               ushort_t* __restrict__ dh,
                                               ushort_t* __restrict__ dl, int n) {
    int i = blockIdx.x * 256 + threadIdx.x;
    if (i < n) {
        float v = src[i];
        ushort_t h = f2b(v);
        dh[i] = h;
        if (dl) dl[i] = f2b(v - bf2f(h));
    }
}

// ---------------- Wqkv pack with head-interleaved q/k rows ----------------
// dst row order per layer: [h0q(32) h0k(32) h1q(32) h1k(32) ... h7q h7k, v(256)]
// src layout per layer (3,8,32,256): row = x*256 + h*32 + d
__global__ __launch_bounds__(256) void wqkv_pack_k(const float* __restrict__ src,
                                                   ushort_t* __restrict__ dh,
                                                   ushort_t* __restrict__ dl) {
    int i = blockIdx.x * 256 + threadIdx.x;      // 589,824 total
    if (i >= 589824) return;
    int c = i & 255;
    int rr = (i >> 8) % 768;
    int a = i / (768 * 256);
    int srcrow;
    if (rr < 512) {
        int head = rr >> 6, half = (rr >> 5) & 1, d = rr & 31;
        srcrow = half * 256 + head * 32 + d;
    } else {
        srcrow = rr;                              // v rows already at 512..767
    }
    float v = src[((size_t)a * 768 + srcrow) * 256 + c];
    ushort_t h = f2b(v);
    dh[i] = h;
    dl[i] = f2b(v - bf2f(h));
}

// ---------------- row 0 of each batch: cls + bias ----------------
__global__ __launch_bounds__(256) void row0_k(float* __restrict__ out,
                                              const float* __restrict__ cls,
                                              const float* __restrict__ bias) {
    int i = blockIdx.x, t = threadIdx.x;
    size_t o = (size_t)i * BP1 * CC + t;
    out[o] = cls[i * CC + t] + bias[o];
}

// ---------------- layernorm f32 -> bf16 plane(s) (lo optional) ----------------
__global__ __launch_bounds__(256) void ln_k(const float* __restrict__ in,
                                            ushort_t* __restrict__ zh, ushort_t* __restrict__ zl,
                                            const float* __restrict__ g, const float* __restrict__ b) {
    int row = blockIdx.x * 4 + (threadIdx.x >> 6);
    int lane = threadIdx.x & 63;
    const float4 v = *reinterpret_cast<const float4*>(in + (size_t)row * CC + lane * 4);
    float s = v.x + v.y + v.z + v.w;
    float sq = v.x * v.x + v.y * v.y + v.z * v.z + v.w * v.w;
    #pragma unroll
    for (int m = 1; m < 64; m <<= 1) { s += __shfl_xor(s, m); sq += __shfl_xor(sq, m); }
    float mu = s * (1.0f / CC);
    float var = sq * (1.0f / CC) - mu * mu;
    float rs = rsqrtf(var + 1e-5f);
    const float4 gg = *reinterpret_cast<const float4*>(g + lane * 4);
    const float4 bb = *reinterpret_cast<const float4*>(b + lane * 4);
    float o[4];
    o[0] = (v.x - mu) * rs * gg.x + bb.x;
    o[1] = (v.y - mu) * rs * gg.y + bb.y;
    o[2] = (v.z - mu) * rs * gg.z + bb.z;
    o[3] = (v.w - mu) * rs * gg.w + bb.w;
    ushort4 hs;
    hs.x = f2b(o[0]); hs.y = f2b(o[1]); hs.z = f2b(o[2]); hs.w = f2b(o[3]);
    size_t base = (size_t)row * CC + lane * 4;
    *reinterpret_cast<ushort4*>(zh + base) = hs;
    if (zl) {
        ushort4 ls;
        ls.x = f2b(o[0] - bf2f(hs.x));
        ls.y = f2b(o[1] - bf2f(hs.y));
        ls.z = f2b(o[2] - bf2f(hs.z));
        ls.w = f2b(o[3] - bf2f(hs.w));
        *reinterpret_cast<ushort4*>(zl + base) = ls;
    }
}

// ---------------- cumsum pass 1: per-chunk totals of rsa*v (32 chunks x 64 rows) ----------------
__global__ __launch_bounds__(256) void cumsum1_k(const float* __restrict__ v,
                                                 const float* __restrict__ rsa,
                                                 float* __restrict__ tot) {
    int bi = blockIdx.x >> 5, ch = blockIdx.x & 31, c = threadIdx.x;
    int h = c >> 5;
    size_t row0 = (size_t)bi * BP1 + ch * 64;
    float s = 0.f;
    for (int j = 0; j < 64; ++j)
        s += v[(row0 + j) * CC + c] * rsa[(row0 + j) * 8 + h];
    tot[((size_t)bi * 32 + ch) * CC + c] = s;
}

// ---------------- cumsum pass 2: scan rsa*v + offset -> split planes ----------------
__global__ __launch_bounds__(256) void cumsum2_k(const float* __restrict__ v,
                                                 const float* __restrict__ rsa,
                                                 const float* __restrict__ tot,
                                                 ushort_t* __restrict__ ph,
                                                 ushort_t* __restrict__ pl) {
    int bi = blockIdx.x / 33, ch = blockIdx.x - bi * 33, c = threadIdx.x;
    int h = c >> 5;
    if (ch == 32) {   // row BB (untouched by cumsum): scale + split-pack
        size_t row = (size_t)bi * BP1 + BB;
        float val = v[row * CC + c] * rsa[row * 8 + h];
        ushort_t hh = f2b(val);
        ph[row * CC + c] = hh; pl[row * CC + c] = f2b(val - bf2f(hh));
        return;
    }
    float s = 0.f;
    for (int q = 0; q < ch; ++q) s += tot[((size_t)bi * 32 + q) * CC + c];
    size_t row0 = (size_t)bi * BP1 + ch * 64;
    for (int j = 0; j < 64; ++j) {
        size_t row = row0 + j;
        s += v[row * CC + c] * rsa[row * 8 + h];
        ushort_t hh = f2b(s);
        ph[row * CC + c] = hh;
        pl[row * CC + c] = f2b(s - bf2f(hh));
    }
}

// ---------------- split-bf16 MFMA GEMM (round-9 structure, proven best) ----------------
// Out(MxN) = A(MxK) * W(NxK)^T ; 1-D grid = NT*MT, XCD-bijective swizzle, n-fastest raster.
// ALO: A lo plane present (3-term). WLO: W lo plane present. fc1 uses <0,0> (1-term).
// F_QKV (head-interleaved W): qk tiles (cols<512) -> in-register rsa (Op, fp32);
//                             v tiles -> fp32 vbuf (Op2).
template<int ALO, int WLO>
__global__ __launch_bounds__(256) void mm_k(const ushort_t* __restrict__ Ah_g,
                                            const ushort_t* __restrict__ Al_g,
                                            const ushort_t* __restrict__ Bh_g,
                                            const ushort_t* __restrict__ Bl_g,
                                            void* __restrict__ Op,
                                            void* __restrict__ Op2,
                                            const float* __restrict__ bias,
                                            int M, int K, int NC, int NT, int flags) {
    __shared__ __align__(16) short As_h[4096];
    __shared__ __align__(16) short As_l[4096];
    __shared__ __align__(16) short Bs_h[4096];
    __shared__ __align__(16) short Bs_l[4096];
    const int t = threadIdx.x;

    // XCD-bijective block swizzle (m204)
    const int nwg = gridDim.x;
    const int q8 = nwg >> 3, r8 = nwg & 7;
    const int xcd = blockIdx.x & 7, ii = blockIdx.x >> 3;
    const int wgid = (xcd < r8 ? xcd * (q8 + 1) : r8 * (q8 + 1) + (xcd - r8) * q8) + ii;
    const int nt = wgid % NT, mt = wgid / NT;
    const int n0 = nt * 128, m0 = mt * 128;

    const int wid = t >> 6, l = t & 63;
    const int wr = wid >> 1, wc = wid & 1;

    // staging geometry: wave w covers 1KB chunks (w) and (w+4); lane l -> row l>>2, col (l&3)*8
    const int ch0 = wid, ch1 = wid + 4;
    const int sr0 = ch0 * 16 + (l >> 2);
    const int sr1 = ch1 * 16 + (l >> 2);
    const int sc  = (l & 3) * 8;
    int ga0 = m0 + sr0; if (ga0 >= M) ga0 = M - 1;
    int ga1 = m0 + sr1; if (ga1 >= M) ga1 = M - 1;
    const int gb0 = n0 + sr0, gb1 = n0 + sr1;

    f32x4 acc[4][4];
    #pragma unroll
    for (int i = 0; i < 4; ++i)
        #pragma unroll
        for (int j = 0; j < 4; ++j) acc[i][j] = (f32x4)(0.0f);

    for (int k0 = 0; k0 < K; k0 += 32) {
        gload16(Ah_g + (size_t)ga0 * K + k0 + sc, &As_h[ch0 * 512]);
        gload16(Ah_g + (size_t)ga1 * K + k0 + sc, &As_h[ch1 * 512]);
        if (ALO) {
            gload16(Al_g + (size_t)ga0 * K + k0 + sc, &As_l[ch0 * 512]);
            gload16(Al_g + (size_t)ga1 * K + k0 + sc, &As_l[ch1 * 512]);
        }
        gload16(Bh_g + (size_t)gb0 * K + k0 + sc, &Bs_h[ch0 * 512]);
        gload16(Bh_g + (size_t)gb1 * K + k0 + sc, &Bs_h[ch1 * 512]);
        if (WLO) {
            gload16(Bl_g + (size_t)gb0 * K + k0 + sc, &Bs_l[ch0 * 512]);
            gload16(Bl_g + (size_t)gb1 * K + k0 + sc, &Bs_l[ch1 * 512]);
        }
        __syncthreads();
        short8 ah[4], al[4], bh[4], bl[4];
        #pragma unroll
        for (int i = 0; i < 4; ++i) {
            int ro = (wr * 64 + i * 16 + (l & 15)) * 32 + (l >> 4) * 8;
            ah[i] = *reinterpret_cast<const short8*>(&As_h[ro]);
            if (ALO) al[i] = *reinterpret_cast<const short8*>(&As_l[ro]);
        }
        #pragma unroll
        for (int j = 0; j < 4; ++j) {
            int ro = (wc * 64 + j * 16 + (l & 15)) * 32 + (l >> 4) * 8;
            bh[j] = *reinterpret_cast<const short8*>(&Bs_h[ro]);
            if (WLO) bl[j] = *reinterpret_cast<const short8*>(&Bs_l[ro]);
        }
        #pragma unroll
        for (int i = 0; i < 4; ++i)
            #pragma unroll
            for (int j = 0; j < 4; ++j) {
                acc[i][j] = __builtin_amdgcn_mfma_f32_16x16x32_bf16(ah[i], bh[j], acc[i][j], 0, 0, 0);
                if (WLO)
                    acc[i][j] = __builtin_amdgcn_mfma_f32_16x16x32_bf16(ah[i], bl[j], acc[i][j], 0, 0, 0);
                if (ALO)
                    acc[i][j] = __builtin_amdgcn_mfma_f32_16x16x32_bf16(al[i], bh[j], acc[i][j], 0, 0, 0);
            }
        __syncthreads();
    }

    // ---- F_QKV epilogue: fused rsa (qk tiles) / vbuf store (v tiles) ----
    if (flags & F_QKV) {
        const int cb0 = n0 + wc * 64;             // wave-uniform
        if (cb0 < 512) {                          // head-interleaved q/k tile
            float* rsaO = reinterpret_cast<float*>(Op);
            const int head = cb0 >> 6;            // 64 cols per head: q(32)|k(32)
            #pragma unroll
            for (int i = 0; i < 4; ++i)
                #pragma unroll
                for (int r = 0; r < 4; ++r) {
                    // q d=(j*16+(l&15)) for j=0,1 ; k same d at j=2,3
                    float p = acc[i][0][r] * acc[i][2][r] + acc[i][1][r] * acc[i][3][r];
                    p += __shfl_xor(p, 1); p += __shfl_xor(p, 2);
                    p += __shfl_xor(p, 4); p += __shfl_xor(p, 8);
                    int row = m0 + wr * 64 + i * 16 + (l >> 4) * 4 + r;
                    if ((l & 15) == 0 && row < M)
                        rsaO[(size_t)row * 8 + head] = p * 0.17677669529663689f;
                }
        } else {                                  // v tile -> fp32 vbuf
            float* vO = reinterpret_cast<float*>(Op2);
            #pragma unroll
            for (int i = 0; i < 4; ++i)
                #pragma unroll
                for (int j = 0; j < 4; ++j) {
                    int colb = cb0 + j * 16 + (l & 15) - 512;
                    #pragma unroll
                    for (int r = 0; r < 4; ++r) {
                        int row = m0 + wr * 64 + i * 16 + (l >> 4) * 4 + r;
                        if (row < M) vO[(size_t)row * 256 + colb] = acc[i][j][r];
                    }
                }
        }
        return;
    }

    // ---- general epilogue ----
    #pragma unroll
    for (int i = 0; i < 4; ++i)
        #pragma unroll
        for (int j = 0; j < 4; ++j) {
            int colb = n0 + wc * 64 + j * 16 + (l & 15);
            #pragma unroll
            for (int r = 0; r < 4; ++r) {
                int row = m0 + wr * 64 + i * 16 + (l >> 4) * 4 + r;
                if (row >= M) continue;
                float v = acc[i][j][r];
                size_t g = (flags & F_ROWMAP) ? ((size_t)(row >> 11) * BP1 + 1 + (row & 2047))
                                             : (size_t)row;
                if (flags & F_BIAS1D) v += bias[colb];
                if (flags & F_BIAS2D) v += bias[g * (size_t)NC + colb];
                if (flags & F_GELU) {   // tanh-form GELU: v * sigmoid(1.5958v + 0.07135v^3)
                    float z = v * (1.595769122f + 0.071354816f * v * v);
                    v = v / (1.0f + __expf(-z));
                }
                size_t oi = g * (size_t)NC + colb;
                if (flags & F_OUTB16) {
                    reinterpret_cast<ushort_t*>(Op)[oi] = f2b(v);
                } else {
                    float* O = reinterpret_cast<float*>(Op);
                    if (flags & F_RESID) v += O[oi];
                    O[oi] = v;
                }
            }
        }
}

// ---------------- launch ----------------
extern "C" void kernel_launch(void* const* d_in, const int* in_sizes, int n_in,
                              void* d_out, int out_size, void* d_ws, size_t ws_size,
                              hipStream_t stream) {
    const float* x      = (const float*)d_in[0];
    const float* weight = (const float*)d_in[1];
    const float* bias   = (const float*)d_in[2];
    const float* cls    = (const float*)d_in[3];
    const float* Wqkv   = (const float*)d_in[4];
    const float* Wo     = (const float*)d_in[5];
    const float* ln1_g  = (const float*)d_in[6];
    const float* ln1_b  = (const float*)d_in[7];
    const float* ln2_g  = (const float*)d_in[8];
    const float* ln2_b  = (const float*)d_in[9];
    const float* fc1_w  = (const float*)d_in[10];
    const float* fc1_b  = (const float*)d_in[11];
    const float* fc2_w  = (const float*)d_in[12];
    const float* fc2_b  = (const float*)d_in[13];
    float* out = (float*)d_out;

    // ---- workspace (high-water 209,290,240 B — proven rounds 7-15) ----
    // zh  [0,          33,570,816)   z hi plane (x hi pre-embed)
    // tot [33,570,816, 34,619,392)   32*32*256 f32 (dead zl region)
    // R1  [67,141,632,134,283,264)   vbuf f32 -> hbuf lower half
    // R2  [134,283,264,201,424,896)  imh+iml planes -> hbuf upper half
    // rsa [201,424,896,203,523,072)
    // wp  [203,785,216,209,290,240)  weight planes (hi|lo per weight)
    char* ws = (char*)d_ws;
    ushort_t* zh    = (ushort_t*)(ws + 0);
    float*    tot   = (float*)(ws + 33570816);
    float*    vbuf  = (float*)(ws + 67141632);
    ushort_t* imh   = (ushort_t*)(ws + 134283264);
    ushort_t* iml   = (ushort_t*)(ws + 167854080);
    ushort_t* hbuf  = (ushort_t*)(ws + 67141632);              // spans R1+R2
    float*    rsa   = (float*)(ws + 201424896);
    ushort_t* wp    = (ushort_t*)(ws + 203785216);

    ushort_t* w_h    = wp;                 // weight  65,536
    ushort_t* w_l    = wp + 65536;
    ushort_t* wqkv_h = wp + 131072;        // Wqkv   589,824 (head-interleaved)
    ushort_t* wqkv_l = wp + 720896;
    ushort_t* wo_h   = wp + 1310720;       // Wo     196,608
    ushort_t* wo_l   = wp + 1507328;
    ushort_t* fc1_h  = wp + 1703936;       // fc1    262,144
    ushort_t* fc1_l  = wp + 1966080;       // (unused this round)
    ushort_t* fc2_h  = wp + 2228224;       // fc2    262,144
    ushort_t* fc2_l  = wp + 2490368;       // end 2,752,512 -> 209,290,240 B

    pack2_k<<<256,  256, 0, stream>>>(weight, w_h,    w_l,    65536);
    wqkv_pack_k<<<2304, 256, 0, stream>>>(Wqkv, wqkv_h, wqkv_l);
    pack2_k<<<768,  256, 0, stream>>>(Wo,     wo_h,   wo_l,   196608);
    pack2_k<<<1024, 256, 0, stream>>>(fc1_w,  fc1_h,  nullptr, 262144);
    pack2_k<<<1024, 256, 0, stream>>>(fc2_w,  fc2_h,  fc2_l,  262144);
    // pack x hi-only into zh (consumed by embed GEMM, then ln_k overwrites)
    pack2_k<<<65536, 256, 0, stream>>>(x, zh, nullptr, AA * BB * CC);

    row0_k<<<AA, 256, 0, stream>>>(out, cls, bias);
    // embed: out[i,1+j,:] = x[i,j,:] @ weight^T + bias  (2-term: x hi only)
    mm_k<0,1><<<1024, 256, 0, stream>>>(zh, nullptr, w_h, w_l, out, nullptr, bias,
                                        AA * BB, CC, CC, 2, F_ROWMAP | F_BIAS2D);

    const int MT = (NROWS + 127) / 128;   // 513
    for (int a = 0; a < NBLK; ++a) {
        const size_t aw = (size_t)a * 196608;   // per-layer Wqkv stride
        ln_k<<<NROWS / 4, 256, 0, stream>>>(out, zh, nullptr, ln1_g, ln1_b);
        // fused qkv: qk tiles -> rsa in-register (fp32), v tiles -> vbuf
        mm_k<0,1><<<6 * MT, 256, 0, stream>>>(zh, nullptr, wqkv_h + aw, wqkv_l + aw,
                                              rsa, vbuf, nullptr,
                                              NROWS, CC, 768, 6, F_QKV);
        cumsum1_k<<<1024, 256, 0, stream>>>(vbuf, rsa, tot);
        cumsum2_k<<<1056, 256, 0, stream>>>(vbuf, rsa, tot, imh, iml);
        // savespace += im @ Wo^T  (3-term: im is the large-magnitude cumsum tensor)
        mm_k<1,1><<<2 * MT, 256, 0, stream>>>(imh, iml, wo_h + (size_t)a * 65536,
                                              wo_l + (size_t)a * 65536, out, nullptr, nullptr,
                                              NROWS, CC, CC, 2, F_RESID);
        ln_k<<<NROWS / 4, 256, 0, stream>>>(out, zh, nullptr, ln2_g, ln2_b);
        // h = gelu(z @ fc1^T + b) -> bf16 hbuf  (1-term: zh x fc1 hi)
        mm_k<0,0><<<8 * MT, 256, 0, stream>>>(zh, nullptr, fc1_h, nullptr, hbuf, nullptr, fc1_b,
                                              NROWS, CC, FFN, 8, F_BIAS1D | F_GELU | F_OUTB16);
        // savespace += h @ fc2^T + b  (2-term: h single plane, fc2 hi+lo)
        mm_k<0,1><<<2 * MT, 256, 0, stream>>>(hbuf, nullptr, fc2_h, fc2_l, out, nullptr, fc2_b,
                                              NROWS, FFN, CC, 2, F_BIAS1D | F_RESID);
    }
}

// Round 17
// 1444.702 us; speedup vs baseline: 1.9410x; 1.1799x over previous
//
#include <hip/hip_runtime.h>
#include <math.h>

#define AA 32
#define BB 2048
#define BP1 2049
#define CC 256
#define NROWS (AA * BP1)          // 65568
#define NBLK 3
#define FFN 1024

typedef unsigned int uint;
typedef unsigned short ushort_t;
typedef __attribute__((ext_vector_type(4))) float f32x4;
typedef __attribute__((ext_vector_type(8))) short short8;

// epilogue flag bits for mm_k (wave-uniform runtime flags)
#define F_ROWMAP 2
#define F_BIAS2D 4
#define F_BIAS1D 8
#define F_GELU   16
#define F_RESID  32
#define F_OUTB16 64
#define F_QKV    128

__device__ __forceinline__ float bf2f(ushort_t u) {
    return __uint_as_float(((uint)u) << 16);
}
__device__ __forceinline__ ushort_t f2b(float x) {   // fp32 -> bf16 RNE
    uint u = __float_as_uint(x);
    u += 0x7fff + ((u >> 16) & 1);
    return (ushort_t)(u >> 16);
}

// global -> LDS direct 16B load
typedef const uint __attribute__((address_space(1)))* gas_t;
typedef uint __attribute__((address_space(3)))* las_t;
__device__ __forceinline__ void gload16(const ushort_t* g, const short* l) {
    __builtin_amdgcn_global_load_lds(
        reinterpret_cast<gas_t>(reinterpret_cast<uintptr_t>(g)),
        reinterpret_cast<las_t>(static_cast<uint>(reinterpret_cast<uintptr_t>(l))),
        16, 0, 0);
}

// ---------------- fp32 -> bf16 planes (lo plane optional) ----------------
__global__ __launch_bounds__(256) void pack2_k(const float* __restrict__ src,
                                               ushort_t* __restrict__ dh,
                                               ushort_t* __restrict__ dl, int n) {
    int i = blockIdx.x * 256 + threadIdx.x;
    if (i < n) {
        float v = src[i];
        ushort_t h = f2b(v);
        dh[i] = h;
        if (dl) dl[i] = f2b(v - bf2f(h));
    }
}

// ---------------- Wqkv pack with head-interleaved q/k rows ----------------
// dst row order per layer: [h0q(32) h0k(32) h1q(32) h1k(32) ... h7q h7k, v(256)]
// src layout per layer (3,8,32,256): row = x*256 + h*32 + d
__global__ __launch_bounds__(256) void wqkv_pack_k(const float* __restrict__ src,
                                                   ushort_t* __restrict__ dh,
                                                   ushort_t* __restrict__ dl) {
    int i = blockIdx.x * 256 + threadIdx.x;      // 589,824 total
    if (i >= 589824) return;
    int c = i & 255;
    int rr = (i >> 8) % 768;
    int a = i / (768 * 256);
    int srcrow;
    if (rr < 512) {
        int head = rr >> 6, half = (rr >> 5) & 1, d = rr & 31;
        srcrow = half * 256 + head * 32 + d;
    } else {
        srcrow = rr;                              // v rows already at 512..767
    }
    float v = src[((size_t)a * 768 + srcrow) * 256 + c];
    ushort_t h = f2b(v);
    dh[i] = h;
    dl[i] = f2b(v - bf2f(h));
}

// ---------------- row 0 of each batch: cls + bias ----------------
__global__ __launch_bounds__(256) void row0_k(float* __restrict__ out,
                                              const float* __restrict__ cls,
                                              const float* __restrict__ bias) {
    int i = blockIdx.x, t = threadIdx.x;
    size_t o = (size_t)i * BP1 * CC + t;
    out[o] = cls[i * CC + t] + bias[o];
}

// ---------------- layernorm f32 -> bf16 plane(s) (lo optional) ----------------
__global__ __launch_bounds__(256) void ln_k(const float* __restrict__ in,
                                            ushort_t* __restrict__ zh, ushort_t* __restrict__ zl,
                                            const float* __restrict__ g, const float* __restrict__ b) {
    int row = blockIdx.x * 4 + (threadIdx.x >> 6);
    int lane = threadIdx.x & 63;
    const float4 v = *reinterpret_cast<const float4*>(in + (size_t)row * CC + lane * 4);
    float s = v.x + v.y + v.z + v.w;
    float sq = v.x * v.x + v.y * v.y + v.z * v.z + v.w * v.w;
    #pragma unroll
    for (int m = 1; m < 64; m <<= 1) { s += __shfl_xor(s, m); sq += __shfl_xor(sq, m); }
    float mu = s * (1.0f / CC);
    float var = sq * (1.0f / CC) - mu * mu;
    float rs = rsqrtf(var + 1e-5f);
    const float4 gg = *reinterpret_cast<const float4*>(g + lane * 4);
    const float4 bb = *reinterpret_cast<const float4*>(b + lane * 4);
    float o[4];
    o[0] = (v.x - mu) * rs * gg.x + bb.x;
    o[1] = (v.y - mu) * rs * gg.y + bb.y;
    o[2] = (v.z - mu) * rs * gg.z + bb.z;
    o[3] = (v.w - mu) * rs * gg.w + bb.w;
    ushort4 hs;
    hs.x = f2b(o[0]); hs.y = f2b(o[1]); hs.z = f2b(o[2]); hs.w = f2b(o[3]);
    size_t base = (size_t)row * CC + lane * 4;
    *reinterpret_cast<ushort4*>(zh + base) = hs;
    if (zl) {
        ushort4 ls;
        ls.x = f2b(o[0] - bf2f(hs.x));
        ls.y = f2b(o[1] - bf2f(hs.y));
        ls.z = f2b(o[2] - bf2f(hs.z));
        ls.w = f2b(o[3] - bf2f(hs.w));
        *reinterpret_cast<ushort4*>(zl + base) = ls;
    }
}

// ---------------- cumsum pass 1: per-chunk totals of rsa*v (32 chunks x 64 rows) ----------------
__global__ __launch_bounds__(256) void cumsum1_k(const float* __restrict__ v,
                                                 const float* __restrict__ rsa,
                                                 float* __restrict__ tot) {
    int bi = blockIdx.x >> 5, ch = blockIdx.x & 31, c = threadIdx.x;
    int h = c >> 5;
    size_t row0 = (size_t)bi * BP1 + ch * 64;
    float s = 0.f;
    for (int j = 0; j < 64; ++j)
        s += v[(row0 + j) * CC + c] * rsa[(row0 + j) * 8 + h];
    tot[((size_t)bi * 32 + ch) * CC + c] = s;
}

// ---------------- cumsum pass 2: scan rsa*v + offset -> split planes ----------------
__global__ __launch_bounds__(256) void cumsum2_k(const float* __restrict__ v,
                                                 const float* __restrict__ rsa,
                                                 const float* __restrict__ tot,
                                                 ushort_t* __restrict__ ph,
                                                 ushort_t* __restrict__ pl) {
    int bi = blockIdx.x / 33, ch = blockIdx.x - bi * 33, c = threadIdx.x;
    int h = c >> 5;
    if (ch == 32) {   // row BB (untouched by cumsum): scale + split-pack
        size_t row = (size_t)bi * BP1 + BB;
        float val = v[row * CC + c] * rsa[row * 8 + h];
        ushort_t hh = f2b(val);
        ph[row * CC + c] = hh; pl[row * CC + c] = f2b(val - bf2f(hh));
        return;
    }
    float s = 0.f;
    for (int q = 0; q < ch; ++q) s += tot[((size_t)bi * 32 + q) * CC + c];
    size_t row0 = (size_t)bi * BP1 + ch * 64;
    for (int j = 0; j < 64; ++j) {
        size_t row = row0 + j;
        s += v[row * CC + c] * rsa[row * 8 + h];
        ushort_t hh = f2b(s);
        ph[row * CC + c] = hh;
        pl[row * CC + c] = f2b(s - bf2f(hh));
    }
}

// ---------------- split-bf16 MFMA GEMM, operand-swapped fragments ----------------
// Out(MxN) = A(MxK) * W(NxK)^T ; 1-D grid = NT*MT, XCD-bijective swizzle.
// MFMA computed as mfma(B,A,acc) -> lane holds Out[row = ..+(l&15)][4 consecutive cols].
// ALO: A lo plane (3-term). WLO: W lo plane. fc1 uses <0,0> (1-term).
// F_QKV (head-interleaved W): qk tiles (cols<512) -> in-register rsa; v tiles -> float4 vbuf.
template<int ALO, int WLO>
__global__ __launch_bounds__(256) void mm_k(const ushort_t* __restrict__ Ah_g,
                                            const ushort_t* __restrict__ Al_g,
                                            const ushort_t* __restrict__ Bh_g,
                                            const ushort_t* __restrict__ Bl_g,
                                            void* __restrict__ Op,
                                            void* __restrict__ Op2,
                                            const float* __restrict__ bias,
                                            int M, int K, int NC, int NT, int flags) {
    __shared__ __align__(16) short As_h[4096];
    __shared__ __align__(16) short As_l[4096];
    __shared__ __align__(16) short Bs_h[4096];
    __shared__ __align__(16) short Bs_l[4096];
    const int t = threadIdx.x;

    // XCD-bijective block swizzle (m204)
    const int nwg = gridDim.x;
    const int q8 = nwg >> 3, r8 = nwg & 7;
    const int xcd = blockIdx.x & 7, ii = blockIdx.x >> 3;
    const int wgid = (xcd < r8 ? xcd * (q8 + 1) : r8 * (q8 + 1) + (xcd - r8) * q8) + ii;
    const int nt = wgid % NT, mt = wgid / NT;
    const int n0 = nt * 128, m0 = mt * 128;

    const int wid = t >> 6, l = t & 63;
    const int wr = wid >> 1, wc = wid & 1;

    // staging geometry: wave w covers 1KB chunks (w) and (w+4); lane l -> row l>>2, col (l&3)*8
    const int ch0 = wid, ch1 = wid + 4;
    const int sr0 = ch0 * 16 + (l >> 2);
    const int sr1 = ch1 * 16 + (l >> 2);
    const int sc  = (l & 3) * 8;
    int ga0 = m0 + sr0; if (ga0 >= M) ga0 = M - 1;
    int ga1 = m0 + sr1; if (ga1 >= M) ga1 = M - 1;
    const int gb0 = n0 + sr0, gb1 = n0 + sr1;

    f32x4 acc[4][4];
    #pragma unroll
    for (int i = 0; i < 4; ++i)
        #pragma unroll
        for (int j = 0; j < 4; ++j) acc[i][j] = (f32x4)(0.0f);

    for (int k0 = 0; k0 < K; k0 += 32) {
        gload16(Ah_g + (size_t)ga0 * K + k0 + sc, &As_h[ch0 * 512]);
        gload16(Ah_g + (size_t)ga1 * K + k0 + sc, &As_h[ch1 * 512]);
        if (ALO) {
            gload16(Al_g + (size_t)ga0 * K + k0 + sc, &As_l[ch0 * 512]);
            gload16(Al_g + (size_t)ga1 * K + k0 + sc, &As_l[ch1 * 512]);
        }
        gload16(Bh_g + (size_t)gb0 * K + k0 + sc, &Bs_h[ch0 * 512]);
        gload16(Bh_g + (size_t)gb1 * K + k0 + sc, &Bs_h[ch1 * 512]);
        if (WLO) {
            gload16(Bl_g + (size_t)gb0 * K + k0 + sc, &Bs_l[ch0 * 512]);
            gload16(Bl_g + (size_t)gb1 * K + k0 + sc, &Bs_l[ch1 * 512]);
        }
        __syncthreads();
        short8 ah[4], al[4], bh[4], bl[4];
        #pragma unroll
        for (int i = 0; i < 4; ++i) {
            int ro = (wr * 64 + i * 16 + (l & 15)) * 32 + (l >> 4) * 8;
            ah[i] = *reinterpret_cast<const short8*>(&As_h[ro]);
            if (ALO) al[i] = *reinterpret_cast<const short8*>(&As_l[ro]);
        }
        #pragma unroll
        for (int j = 0; j < 4; ++j) {
            int ro = (wc * 64 + j * 16 + (l & 15)) * 32 + (l >> 4) * 8;
            bh[j] = *reinterpret_cast<const short8*>(&Bs_h[ro]);
            if (WLO) bl[j] = *reinterpret_cast<const short8*>(&Bs_l[ro]);
        }
        // operand-swapped: D = B^T-fragment x A -> lane = one row x 4 consecutive cols
        #pragma unroll
        for (int i = 0; i < 4; ++i)
            #pragma unroll
            for (int j = 0; j < 4; ++j) {
                acc[i][j] = __builtin_amdgcn_mfma_f32_16x16x32_bf16(bh[j], ah[i], acc[i][j], 0, 0, 0);
                if (WLO)
                    acc[i][j] = __builtin_amdgcn_mfma_f32_16x16x32_bf16(bl[j], ah[i], acc[i][j], 0, 0, 0);
                if (ALO)
                    acc[i][j] = __builtin_amdgcn_mfma_f32_16x16x32_bf16(bh[j], al[i], acc[i][j], 0, 0, 0);
            }
        __syncthreads();
    }

    // ---- F_QKV epilogue (swapped layout) ----
    if (flags & F_QKV) {
        const int cb0 = n0 + wc * 64;             // wave-uniform
        if (cb0 < 512) {                          // head-interleaved q/k tile
            float* rsaO = reinterpret_cast<float*>(Op);
            const int head = cb0 >> 6;            // 64 cols per head: q(32)|k(32)
            #pragma unroll
            for (int i = 0; i < 4; ++i) {
                int row = m0 + wr * 64 + i * 16 + (l & 15);
                float p = 0.f;
                #pragma unroll
                for (int j = 0; j < 2; ++j)
                    #pragma unroll
                    for (int r = 0; r < 4; ++r)
                        p += acc[i][j][r] * acc[i][j + 2][r];
                p += __shfl_xor(p, 16);
                p += __shfl_xor(p, 32);
                if (l < 16 && row < M)
                    rsaO[(size_t)row * 8 + head] = p * 0.17677669529663689f;
            }
        } else {                                  // v tile -> float4 vbuf
            float* vO = reinterpret_cast<float*>(Op2);
            #pragma unroll
            for (int i = 0; i < 4; ++i) {
                int row = m0 + wr * 64 + i * 16 + (l & 15);
                if (row >= M) continue;
                #pragma unroll
                for (int j = 0; j < 4; ++j) {
                    int colb = cb0 + j * 16 + (l >> 4) * 4 - 512;
                    float4 v4 = make_float4(acc[i][j][0], acc[i][j][1], acc[i][j][2], acc[i][j][3]);
                    *reinterpret_cast<float4*>(vO + (size_t)row * 256 + colb) = v4;
                }
            }
        }
        return;
    }

    // ---- general epilogue (swapped layout: per-lane row x 4 consecutive cols) ----
    #pragma unroll
    for (int i = 0; i < 4; ++i) {
        int row = m0 + wr * 64 + i * 16 + (l & 15);
        if (row >= M) continue;
        size_t g = (flags & F_ROWMAP) ? ((size_t)(row >> 11) * BP1 + 1 + (row & 2047))
                                     : (size_t)row;
        #pragma unroll
        for (int j = 0; j < 4; ++j) {
            int col0 = n0 + wc * 64 + j * 16 + (l >> 4) * 4;
            float4 v4 = make_float4(acc[i][j][0], acc[i][j][1], acc[i][j][2], acc[i][j][3]);
            if (flags & F_BIAS1D) {
                const float4 b4 = *reinterpret_cast<const float4*>(bias + col0);
                v4.x += b4.x; v4.y += b4.y; v4.z += b4.z; v4.w += b4.w;
            }
            if (flags & F_BIAS2D) {
                const float4 b4 = *reinterpret_cast<const float4*>(bias + g * (size_t)NC + col0);
                v4.x += b4.x; v4.y += b4.y; v4.z += b4.z; v4.w += b4.w;
            }
            if (flags & F_GELU) {   // tanh-form GELU: v * sigmoid(1.5958v + 0.07135v^3)
                float z0 = v4.x * (1.595769122f + 0.071354816f * v4.x * v4.x);
                float z1 = v4.y * (1.595769122f + 0.071354816f * v4.y * v4.y);
                float z2 = v4.z * (1.595769122f + 0.071354816f * v4.z * v4.z);
                float z3 = v4.w * (1.595769122f + 0.071354816f * v4.w * v4.w);
                v4.x = v4.x / (1.0f + __expf(-z0));
                v4.y = v4.y / (1.0f + __expf(-z1));
                v4.z = v4.z / (1.0f + __expf(-z2));
                v4.w = v4.w / (1.0f + __expf(-z3));
            }
            size_t oi = g * (size_t)NC + col0;
            if (flags & F_OUTB16) {
                uint2 u;
                u.x = (uint)f2b(v4.x) | ((uint)f2b(v4.y) << 16);
                u.y = (uint)f2b(v4.z) | ((uint)f2b(v4.w) << 16);
                *reinterpret_cast<uint2*>(reinterpret_cast<ushort_t*>(Op) + oi) = u;
            } else {
                float* O = reinterpret_cast<float*>(Op) + oi;
                if (flags & F_RESID) {
                    const float4 o4 = *reinterpret_cast<const float4*>(O);
                    v4.x += o4.x; v4.y += o4.y; v4.z += o4.z; v4.w += o4.w;
                }
                *reinterpret_cast<float4*>(O) = v4;
            }
        }
    }
}

// ---------------- launch ----------------
extern "C" void kernel_launch(void* const* d_in, const int* in_sizes, int n_in,
                              void* d_out, int out_size, void* d_ws, size_t ws_size,
                              hipStream_t stream) {
    const float* x      = (const float*)d_in[0];
    const float* weight = (const float*)d_in[1];
    const float* bias   = (const float*)d_in[2];
    const float* cls    = (const float*)d_in[3];
    const float* Wqkv   = (const float*)d_in[4];
    const float* Wo     = (const float*)d_in[5];
    const float* ln1_g  = (const float*)d_in[6];
    const float* ln1_b  = (const float*)d_in[7];
    const float* ln2_g  = (const float*)d_in[8];
    const float* ln2_b  = (const float*)d_in[9];
    const float* fc1_w  = (const float*)d_in[10];
    const float* fc1_b  = (const float*)d_in[11];
    const float* fc2_w  = (const float*)d_in[12];
    const float* fc2_b  = (const float*)d_in[13];
    float* out = (float*)d_out;

    // ---- workspace (high-water 209,290,240 B — proven rounds 7-16) ----
    // zh  [0,          33,570,816)   z hi plane (x hi pre-embed)
    // tot [33,570,816, 34,619,392)   32*32*256 f32 (dead zl region)
    // R1  [67,141,632,134,283,264)   vbuf f32 -> hbuf lower half
    // R2  [134,283,264,201,424,896)  imh+iml planes -> hbuf upper half
    // rsa [201,424,896,203,523,072)
    // wp  [203,785,216,209,290,240)  weight planes (hi|lo per weight)
    char* ws = (char*)d_ws;
    ushort_t* zh    = (ushort_t*)(ws + 0);
    float*    tot   = (float*)(ws + 33570816);
    float*    vbuf  = (float*)(ws + 67141632);
    ushort_t* imh   = (ushort_t*)(ws + 134283264);
    ushort_t* iml   = (ushort_t*)(ws + 167854080);
    ushort_t* hbuf  = (ushort_t*)(ws + 67141632);              // spans R1+R2
    float*    rsa   = (float*)(ws + 201424896);
    ushort_t* wp    = (ushort_t*)(ws + 203785216);

    ushort_t* w_h    = wp;                 // weight  65,536
    ushort_t* w_l    = wp + 65536;
    ushort_t* wqkv_h = wp + 131072;        // Wqkv   589,824 (head-interleaved)
    ushort_t* wqkv_l = wp + 720896;
    ushort_t* wo_h   = wp + 1310720;       // Wo     196,608
    ushort_t* wo_l   = wp + 1507328;
    ushort_t* fc1_h  = wp + 1703936;       // fc1    262,144
    ushort_t* fc1_l  = wp + 1966080;       // (unused)
    ushort_t* fc2_h  = wp + 2228224;       // fc2    262,144
    ushort_t* fc2_l  = wp + 2490368;       // end 2,752,512 -> 209,290,240 B

    pack2_k<<<256,  256, 0, stream>>>(weight, w_h,    w_l,    65536);
    wqkv_pack_k<<<2304, 256, 0, stream>>>(Wqkv, wqkv_h, wqkv_l);
    pack2_k<<<768,  256, 0, stream>>>(Wo,     wo_h,   wo_l,   196608);
    pack2_k<<<1024, 256, 0, stream>>>(fc1_w,  fc1_h,  nullptr, 262144);
    pack2_k<<<1024, 256, 0, stream>>>(fc2_w,  fc2_h,  fc2_l,  262144);
    // pack x hi-only into zh (consumed by embed GEMM, then ln_k overwrites)
    pack2_k<<<65536, 256, 0, stream>>>(x, zh, nullptr, AA * BB * CC);

    row0_k<<<AA, 256, 0, stream>>>(out, cls, bias);
    // embed: out[i,1+j,:] = x[i,j,:] @ weight^T + bias  (2-term: x hi only)
    mm_k<0,1><<<1024, 256, 0, stream>>>(zh, nullptr, w_h, w_l, out, nullptr, bias,
                                        AA * BB, CC, CC, 2, F_ROWMAP | F_BIAS2D);

    const int MT = (NROWS + 127) / 128;   // 513
    for (int a = 0; a < NBLK; ++a) {
        const size_t aw = (size_t)a * 196608;   // per-layer Wqkv stride
        ln_k<<<NROWS / 4, 256, 0, stream>>>(out, zh, nullptr, ln1_g, ln1_b);
        // fused qkv: qk tiles -> rsa in-register (fp32), v tiles -> vbuf
        mm_k<0,1><<<6 * MT, 256, 0, stream>>>(zh, nullptr, wqkv_h + aw, wqkv_l + aw,
                                              rsa, vbuf, nullptr,
                                              NROWS, CC, 768, 6, F_QKV);
        cumsum1_k<<<1024, 256, 0, stream>>>(vbuf, rsa, tot);
        cumsum2_k<<<1056, 256, 0, stream>>>(vbuf, rsa, tot, imh, iml);
        // savespace += im @ Wo^T  (3-term: im is the large-magnitude cumsum tensor)
        mm_k<1,1><<<2 * MT, 256, 0, stream>>>(imh, iml, wo_h + (size_t)a * 65536,
                                              wo_l + (size_t)a * 65536, out, nullptr, nullptr,
                                              NROWS, CC, CC, 2, F_RESID);
        ln_k<<<NROWS / 4, 256, 0, stream>>>(out, zh, nullptr, ln2_g, ln2_b);
        // h = gelu(z @ fc1^T + b) -> bf16 hbuf  (1-term: zh x fc1 hi)
        mm_k<0,0><<<8 * MT, 256, 0, stream>>>(zh, nullptr, fc1_h, nullptr, hbuf, nullptr, fc1_b,
                                              NROWS, CC, FFN, 8, F_BIAS1D | F_GELU | F_OUTB16);
        // savespace += h @ fc2^T + b  (2-term: h single plane, fc2 hi+lo)
        mm_k<0,1><<<2 * MT, 256, 0, stream>>>(hbuf, nullptr, fc2_h, fc2_l, out, nullptr, fc2_b,
                                              NROWS, FFN, CC, 2, F_BIAS1D | F_RESID);
    }
}

// Round 18
// 1370.466 us; speedup vs baseline: 2.0461x; 1.0542x over previous
//
#include <hip/hip_runtime.h>
#include <math.h>

#define AA 32
#define BB 2048
#define BP1 2049
#define CC 256
#define NROWS (AA * BP1)          // 65568
#define NBLK 3
#define FFN 1024

typedef unsigned int uint;
typedef unsigned short ushort_t;
typedef __attribute__((ext_vector_type(4))) float f32x4;
typedef __attribute__((ext_vector_type(8))) short short8;

// epilogue flag bits for mm_k (wave-uniform runtime flags)
#define F_ROWMAP 2
#define F_BIAS2D 4
#define F_BIAS1D 8
#define F_GELU   16
#define F_RESID  32
#define F_OUTB16 64
#define F_QKV    128

__device__ __forceinline__ float bf2f(ushort_t u) {
    return __uint_as_float(((uint)u) << 16);
}
__device__ __forceinline__ ushort_t f2b(float x) {   // fp32 -> bf16 RNE
    uint u = __float_as_uint(x);
    u += 0x7fff + ((u >> 16) & 1);
    return (ushort_t)(u >> 16);
}

// global -> LDS direct 16B load
typedef const uint __attribute__((address_space(1)))* gas_t;
typedef uint __attribute__((address_space(3)))* las_t;
__device__ __forceinline__ void gload16(const ushort_t* g, const short* l) {
    __builtin_amdgcn_global_load_lds(
        reinterpret_cast<gas_t>(reinterpret_cast<uintptr_t>(g)),
        reinterpret_cast<las_t>(static_cast<uint>(reinterpret_cast<uintptr_t>(l))),
        16, 0, 0);
}

// ---------------- fp32 -> bf16 planes (lo plane optional) ----------------
__global__ __launch_bounds__(256) void pack2_k(const float* __restrict__ src,
                                               ushort_t* __restrict__ dh,
                                               ushort_t* __restrict__ dl, int n) {
    int i = blockIdx.x * 256 + threadIdx.x;
    if (i < n) {
        float v = src[i];
        ushort_t h = f2b(v);
        dh[i] = h;
        if (dl) dl[i] = f2b(v - bf2f(h));
    }
}

// ---------------- Wqkv pack with head-interleaved q/k rows ----------------
// dst row order per layer: [h0q(32) h0k(32) h1q(32) h1k(32) ... h7q h7k, v(256)]
// src layout per layer (3,8,32,256): row = x*256 + h*32 + d
__global__ __launch_bounds__(256) void wqkv_pack_k(const float* __restrict__ src,
                                                   ushort_t* __restrict__ dh,
                                                   ushort_t* __restrict__ dl) {
    int i = blockIdx.x * 256 + threadIdx.x;      // 589,824 total
    if (i >= 589824) return;
    int c = i & 255;
    int rr = (i >> 8) % 768;
    int a = i / (768 * 256);
    int srcrow;
    if (rr < 512) {
        int head = rr >> 6, half = (rr >> 5) & 1, d = rr & 31;
        srcrow = half * 256 + head * 32 + d;
    } else {
        srcrow = rr;                              // v rows already at 512..767
    }
    float v = src[((size_t)a * 768 + srcrow) * 256 + c];
    ushort_t h = f2b(v);
    dh[i] = h;
    dl[i] = f2b(v - bf2f(h));
}

// ---------------- row 0 of each batch: cls + bias ----------------
__global__ __launch_bounds__(256) void row0_k(float* __restrict__ out,
                                              const float* __restrict__ cls,
                                              const float* __restrict__ bias) {
    int i = blockIdx.x, t = threadIdx.x;
    size_t o = (size_t)i * BP1 * CC + t;
    out[o] = cls[i * CC + t] + bias[o];
}

// ---------------- layernorm f32 -> bf16 plane(s) (lo optional) ----------------
__global__ __launch_bounds__(256) void ln_k(const float* __restrict__ in,
                                            ushort_t* __restrict__ zh, ushort_t* __restrict__ zl,
                                            const float* __restrict__ g, const float* __restrict__ b) {
    int row = blockIdx.x * 4 + (threadIdx.x >> 6);
    int lane = threadIdx.x & 63;
    const float4 v = *reinterpret_cast<const float4*>(in + (size_t)row * CC + lane * 4);
    float s = v.x + v.y + v.z + v.w;
    float sq = v.x * v.x + v.y * v.y + v.z * v.z + v.w * v.w;
    #pragma unroll
    for (int m = 1; m < 64; m <<= 1) { s += __shfl_xor(s, m); sq += __shfl_xor(sq, m); }
    float mu = s * (1.0f / CC);
    float var = sq * (1.0f / CC) - mu * mu;
    float rs = rsqrtf(var + 1e-5f);
    const float4 gg = *reinterpret_cast<const float4*>(g + lane * 4);
    const float4 bb = *reinterpret_cast<const float4*>(b + lane * 4);
    float o[4];
    o[0] = (v.x - mu) * rs * gg.x + bb.x;
    o[1] = (v.y - mu) * rs * gg.y + bb.y;
    o[2] = (v.z - mu) * rs * gg.z + bb.z;
    o[3] = (v.w - mu) * rs * gg.w + bb.w;
    ushort4 hs;
    hs.x = f2b(o[0]); hs.y = f2b(o[1]); hs.z = f2b(o[2]); hs.w = f2b(o[3]);
    size_t base = (size_t)row * CC + lane * 4;
    *reinterpret_cast<ushort4*>(zh + base) = hs;
    if (zl) {
        ushort4 ls;
        ls.x = f2b(o[0] - bf2f(hs.x));
        ls.y = f2b(o[1] - bf2f(hs.y));
        ls.z = f2b(o[2] - bf2f(hs.z));
        ls.w = f2b(o[3] - bf2f(hs.w));
        *reinterpret_cast<ushort4*>(zl + base) = ls;
    }
}

// ---------------- cumsum pass 1: per-chunk totals of rsa*v (v bf16, 32 x 64 rows) ----------------
__global__ __launch_bounds__(256) void cumsum1_k(const ushort_t* __restrict__ v,
                                                 const float* __restrict__ rsa,
                                                 float* __restrict__ tot) {
    int bi = blockIdx.x >> 5, ch = blockIdx.x & 31, c = threadIdx.x;
    int h = c >> 5;
    size_t row0 = (size_t)bi * BP1 + ch * 64;
    float s = 0.f;
    for (int j = 0; j < 64; ++j)
        s += bf2f(v[(row0 + j) * CC + c]) * rsa[(row0 + j) * 8 + h];
    tot[((size_t)bi * 32 + ch) * CC + c] = s;
}

// ---------------- cumsum pass 2: scan rsa*v + offset -> im hi plane only ----------------
__global__ __launch_bounds__(256) void cumsum2_k(const ushort_t* __restrict__ v,
                                                 const float* __restrict__ rsa,
                                                 const float* __restrict__ tot,
                                                 ushort_t* __restrict__ ph) {
    int bi = blockIdx.x / 33, ch = blockIdx.x - bi * 33, c = threadIdx.x;
    int h = c >> 5;
    if (ch == 32) {   // row BB (untouched by cumsum): scale + pack
        size_t row = (size_t)bi * BP1 + BB;
        float val = bf2f(v[row * CC + c]) * rsa[row * 8 + h];
        ph[row * CC + c] = f2b(val);
        return;
    }
    float s = 0.f;
    for (int q = 0; q < ch; ++q) s += tot[((size_t)bi * 32 + q) * CC + c];
    size_t row0 = (size_t)bi * BP1 + ch * 64;
    for (int j = 0; j < 64; ++j) {
        size_t row = row0 + j;
        s += bf2f(v[row * CC + c]) * rsa[row * 8 + h];
        ph[row * CC + c] = f2b(s);
    }
}

// ---------------- split-bf16 MFMA GEMM, operand-swapped fragments ----------------
// Out(MxN) = A(MxK) * W(NxK)^T ; 1-D grid = NT*MT, XCD-bijective swizzle.
// MFMA computed as mfma(B,A,acc) -> lane holds Out[row = ..+(l&15)][4 consecutive cols].
// ALO: A lo plane (3-term). WLO: W lo plane. fc1 uses <0,0> (1-term).
// F_QKV (head-interleaved W): qk tiles (cols<512) -> in-register rsa; v tiles -> bf16 vbuf.
template<int ALO, int WLO>
__global__ __launch_bounds__(256) void mm_k(const ushort_t* __restrict__ Ah_g,
                                            const ushort_t* __restrict__ Al_g,
                                            const ushort_t* __restrict__ Bh_g,
                                            const ushort_t* __restrict__ Bl_g,
                                            void* __restrict__ Op,
                                            void* __restrict__ Op2,
                                            const float* __restrict__ bias,
                                            int M, int K, int NC, int NT, int flags) {
    __shared__ __align__(16) short As_h[4096];
    __shared__ __align__(16) short As_l[4096];
    __shared__ __align__(16) short Bs_h[4096];
    __shared__ __align__(16) short Bs_l[4096];
    const int t = threadIdx.x;

    // XCD-bijective block swizzle (m204)
    const int nwg = gridDim.x;
    const int q8 = nwg >> 3, r8 = nwg & 7;
    const int xcd = blockIdx.x & 7, ii = blockIdx.x >> 3;
    const int wgid = (xcd < r8 ? xcd * (q8 + 1) : r8 * (q8 + 1) + (xcd - r8) * q8) + ii;
    const int nt = wgid % NT, mt = wgid / NT;
    const int n0 = nt * 128, m0 = mt * 128;

    const int wid = t >> 6, l = t & 63;
    const int wr = wid >> 1, wc = wid & 1;

    // staging geometry: wave w covers 1KB chunks (w) and (w+4); lane l -> row l>>2, col (l&3)*8
    const int ch0 = wid, ch1 = wid + 4;
    const int sr0 = ch0 * 16 + (l >> 2);
    const int sr1 = ch1 * 16 + (l >> 2);
    const int sc  = (l & 3) * 8;
    int ga0 = m0 + sr0; if (ga0 >= M) ga0 = M - 1;
    int ga1 = m0 + sr1; if (ga1 >= M) ga1 = M - 1;
    const int gb0 = n0 + sr0, gb1 = n0 + sr1;

    f32x4 acc[4][4];
    #pragma unroll
    for (int i = 0; i < 4; ++i)
        #pragma unroll
        for (int j = 0; j < 4; ++j) acc[i][j] = (f32x4)(0.0f);

    for (int k0 = 0; k0 < K; k0 += 32) {
        gload16(Ah_g + (size_t)ga0 * K + k0 + sc, &As_h[ch0 * 512]);
        gload16(Ah_g + (size_t)ga1 * K + k0 + sc, &As_h[ch1 * 512]);
        if (ALO) {
            gload16(Al_g + (size_t)ga0 * K + k0 + sc, &As_l[ch0 * 512]);
            gload16(Al_g + (size_t)ga1 * K + k0 + sc, &As_l[ch1 * 512]);
        }
        gload16(Bh_g + (size_t)gb0 * K + k0 + sc, &Bs_h[ch0 * 512]);
        gload16(Bh_g + (size_t)gb1 * K + k0 + sc, &Bs_h[ch1 * 512]);
        if (WLO) {
            gload16(Bl_g + (size_t)gb0 * K + k0 + sc, &Bs_l[ch0 * 512]);
            gload16(Bl_g + (size_t)gb1 * K + k0 + sc, &Bs_l[ch1 * 512]);
        }
        __syncthreads();
        short8 ah[4], al[4], bh[4], bl[4];
        #pragma unroll
        for (int i = 0; i < 4; ++i) {
            int ro = (wr * 64 + i * 16 + (l & 15)) * 32 + (l >> 4) * 8;
            ah[i] = *reinterpret_cast<const short8*>(&As_h[ro]);
            if (ALO) al[i] = *reinterpret_cast<const short8*>(&As_l[ro]);
        }
        #pragma unroll
        for (int j = 0; j < 4; ++j) {
            int ro = (wc * 64 + j * 16 + (l & 15)) * 32 + (l >> 4) * 8;
            bh[j] = *reinterpret_cast<const short8*>(&Bs_h[ro]);
            if (WLO) bl[j] = *reinterpret_cast<const short8*>(&Bs_l[ro]);
        }
        // operand-swapped: D = B^T-fragment x A -> lane = one row x 4 consecutive cols
        #pragma unroll
        for (int i = 0; i < 4; ++i)
            #pragma unroll
            for (int j = 0; j < 4; ++j) {
                acc[i][j] = __builtin_amdgcn_mfma_f32_16x16x32_bf16(bh[j], ah[i], acc[i][j], 0, 0, 0);
                if (WLO)
                    acc[i][j] = __builtin_amdgcn_mfma_f32_16x16x32_bf16(bl[j], ah[i], acc[i][j], 0, 0, 0);
                if (ALO)
                    acc[i][j] = __builtin_amdgcn_mfma_f32_16x16x32_bf16(bh[j], al[i], acc[i][j], 0, 0, 0);
            }
        __syncthreads();
    }

    // ---- F_QKV epilogue (swapped layout) ----
    if (flags & F_QKV) {
        const int cb0 = n0 + wc * 64;             // wave-uniform
        if (cb0 < 512) {                          // head-interleaved q/k tile
            float* rsaO = reinterpret_cast<float*>(Op);
            const int head = cb0 >> 6;            // 64 cols per head: q(32)|k(32)
            #pragma unroll
            for (int i = 0; i < 4; ++i) {
                int row = m0 + wr * 64 + i * 16 + (l & 15);
                float p = 0.f;
                #pragma unroll
                for (int j = 0; j < 2; ++j)
                    #pragma unroll
                    for (int r = 0; r < 4; ++r)
                        p += acc[i][j][r] * acc[i][j + 2][r];
                p += __shfl_xor(p, 16);
                p += __shfl_xor(p, 32);
                if (l < 16 && row < M)
                    rsaO[(size_t)row * 8 + head] = p * 0.17677669529663689f;
            }
        } else {                                  // v tile -> bf16 vbuf (uint2 = 4 bf16)
            ushort_t* vO = reinterpret_cast<ushort_t*>(Op2);
            #pragma unroll
            for (int i = 0; i < 4; ++i) {
                int row = m0 + wr * 64 + i * 16 + (l & 15);
                if (row >= M) continue;
                #pragma unroll
                for (int j = 0; j < 4; ++j) {
                    int colb = cb0 + j * 16 + (l >> 4) * 4 - 512;
                    uint2 u;
                    u.x = (uint)f2b(acc[i][j][0]) | ((uint)f2b(acc[i][j][1]) << 16);
                    u.y = (uint)f2b(acc[i][j][2]) | ((uint)f2b(acc[i][j][3]) << 16);
                    *reinterpret_cast<uint2*>(vO + (size_t)row * 256 + colb) = u;
                }
            }
        }
        return;
    }

    // ---- general epilogue (swapped layout: per-lane row x 4 consecutive cols) ----
    #pragma unroll
    for (int i = 0; i < 4; ++i) {
        int row = m0 + wr * 64 + i * 16 + (l & 15);
        if (row >= M) continue;
        size_t g = (flags & F_ROWMAP) ? ((size_t)(row >> 11) * BP1 + 1 + (row & 2047))
                                     : (size_t)row;
        #pragma unroll
        for (int j = 0; j < 4; ++j) {
            int col0 = n0 + wc * 64 + j * 16 + (l >> 4) * 4;
            float4 v4 = make_float4(acc[i][j][0], acc[i][j][1], acc[i][j][2], acc[i][j][3]);
            if (flags & F_BIAS1D) {
                const float4 b4 = *reinterpret_cast<const float4*>(bias + col0);
                v4.x += b4.x; v4.y += b4.y; v4.z += b4.z; v4.w += b4.w;
            }
            if (flags & F_BIAS2D) {
                const float4 b4 = *reinterpret_cast<const float4*>(bias + g * (size_t)NC + col0);
                v4.x += b4.x; v4.y += b4.y; v4.z += b4.z; v4.w += b4.w;
            }
            if (flags & F_GELU) {   // tanh-form GELU: v * sigmoid(1.5958v + 0.07135v^3)
                float z0 = v4.x * (1.595769122f + 0.071354816f * v4.x * v4.x);
                float z1 = v4.y * (1.595769122f + 0.071354816f * v4.y * v4.y);
                float z2 = v4.z * (1.595769122f + 0.071354816f * v4.z * v4.z);
                float z3 = v4.w * (1.595769122f + 0.071354816f * v4.w * v4.w);
                v4.x = v4.x / (1.0f + __expf(-z0));
                v4.y = v4.y / (1.0f + __expf(-z1));
                v4.z = v4.z / (1.0f + __expf(-z2));
                v4.w = v4.w / (1.0f + __expf(-z3));
            }
            size_t oi = g * (size_t)NC + col0;
            if (flags & F_OUTB16) {
                uint2 u;
                u.x = (uint)f2b(v4.x) | ((uint)f2b(v4.y) << 16);
                u.y = (uint)f2b(v4.z) | ((uint)f2b(v4.w) << 16);
                *reinterpret_cast<uint2*>(reinterpret_cast<ushort_t*>(Op) + oi) = u;
            } else {
                float* O = reinterpret_cast<float*>(Op) + oi;
                if (flags & F_RESID) {
                    const float4 o4 = *reinterpret_cast<const float4*>(O);
                    v4.x += o4.x; v4.y += o4.y; v4.z += o4.z; v4.w += o4.w;
                }
                *reinterpret_cast<float4*>(O) = v4;
            }
        }
    }
}

// ---------------- launch ----------------
extern "C" void kernel_launch(void* const* d_in, const int* in_sizes, int n_in,
                              void* d_out, int out_size, void* d_ws, size_t ws_size,
                              hipStream_t stream) {
    const float* x      = (const float*)d_in[0];
    const float* weight = (const float*)d_in[1];
    const float* bias   = (const float*)d_in[2];
    const float* cls    = (const float*)d_in[3];
    const float* Wqkv   = (const float*)d_in[4];
    const float* Wo     = (const float*)d_in[5];
    const float* ln1_g  = (const float*)d_in[6];
    const float* ln1_b  = (const float*)d_in[7];
    const float* ln2_g  = (const float*)d_in[8];
    const float* ln2_b  = (const float*)d_in[9];
    const float* fc1_w  = (const float*)d_in[10];
    const float* fc1_b  = (const float*)d_in[11];
    const float* fc2_w  = (const float*)d_in[12];
    const float* fc2_b  = (const float*)d_in[13];
    float* out = (float*)d_out;

    // ---- workspace (high-water 209,290,240 B — proven rounds 7-17) ----
    // zh   [0,          33,570,816)   z hi plane (x hi pre-embed)
    // tot  [33,570,816, 34,619,392)   32*32*256 f32
    // vbuf [67,141,632,100,712,448)   v bf16 (R1 lower half; hbuf overlays later)
    // imh  [134,283,264,167,854,080)  im hi plane (R2; hbuf overlays later)
    // hbuf [67,141,632,201,424,896)   spans R1+R2
    // rsa  [201,424,896,203,523,072)
    // wp   [203,785,216,209,290,240)  weight planes (hi|lo per weight)
    char* ws = (char*)d_ws;
    ushort_t* zh    = (ushort_t*)(ws + 0);
    float*    tot   = (float*)(ws + 33570816);
    ushort_t* vbuf  = (ushort_t*)(ws + 67141632);
    ushort_t* imh   = (ushort_t*)(ws + 134283264);
    ushort_t* hbuf  = (ushort_t*)(ws + 67141632);              // spans R1+R2
    float*    rsa   = (float*)(ws + 201424896);
    ushort_t* wp    = (ushort_t*)(ws + 203785216);

    ushort_t* w_h    = wp;                 // weight  65,536
    ushort_t* w_l    = wp + 65536;
    ushort_t* wqkv_h = wp + 131072;        // Wqkv   589,824 (head-interleaved)
    ushort_t* wqkv_l = wp + 720896;
    ushort_t* wo_h   = wp + 1310720;       // Wo     196,608
    ushort_t* wo_l   = wp + 1507328;
    ushort_t* fc1_h  = wp + 1703936;       // fc1    262,144
    ushort_t* fc2_h  = wp + 2228224;       // fc2    262,144
    ushort_t* fc2_l  = wp + 2490368;       // end 2,752,512 -> 209,290,240 B

    pack2_k<<<256,  256, 0, stream>>>(weight, w_h,    w_l,    65536);
    wqkv_pack_k<<<2304, 256, 0, stream>>>(Wqkv, wqkv_h, wqkv_l);
    pack2_k<<<768,  256, 0, stream>>>(Wo,     wo_h,   wo_l,   196608);
    pack2_k<<<1024, 256, 0, stream>>>(fc1_w,  fc1_h,  nullptr, 262144);
    pack2_k<<<1024, 256, 0, stream>>>(fc2_w,  fc2_h,  fc2_l,  262144);
    // pack x hi-only into zh (consumed by embed GEMM, then ln_k overwrites)
    pack2_k<<<65536, 256, 0, stream>>>(x, zh, nullptr, AA * BB * CC);

    row0_k<<<AA, 256, 0, stream>>>(out, cls, bias);
    // embed: out[i,1+j,:] = x[i,j,:] @ weight^T + bias  (2-term: x hi only)
    mm_k<0,1><<<1024, 256, 0, stream>>>(zh, nullptr, w_h, w_l, out, nullptr, bias,
                                        AA * BB, CC, CC, 2, F_ROWMAP | F_BIAS2D);

    const int MT = (NROWS + 127) / 128;   // 513
    for (int a = 0; a < NBLK; ++a) {
        const size_t aw = (size_t)a * 196608;   // per-layer Wqkv stride
        ln_k<<<NROWS / 4, 256, 0, stream>>>(out, zh, nullptr, ln1_g, ln1_b);
        // fused qkv: qk tiles -> rsa in-register (fp32), v tiles -> bf16 vbuf
        mm_k<0,1><<<6 * MT, 256, 0, stream>>>(zh, nullptr, wqkv_h + aw, wqkv_l + aw,
                                              rsa, vbuf, nullptr,
                                              NROWS, CC, 768, 6, F_QKV);
        cumsum1_k<<<1024, 256, 0, stream>>>(vbuf, rsa, tot);
        cumsum2_k<<<1056, 256, 0, stream>>>(vbuf, rsa, tot, imh);
        // savespace += im @ Wo^T  (2-term: im bf16 x Wo hi+lo)
        mm_k<0,1><<<2 * MT, 256, 0, stream>>>(imh, nullptr, wo_h + (size_t)a * 65536,
                                              wo_l + (size_t)a * 65536, out, nullptr, nullptr,
                                              NROWS, CC, CC, 2, F_RESID);
        ln_k<<<NROWS / 4, 256, 0, stream>>>(out, zh, nullptr, ln2_g, ln2_b);
        // h = gelu(z @ fc1^T + b) -> bf16 hbuf  (1-term: zh x fc1 hi)
        mm_k<0,0><<<8 * MT, 256, 0, stream>>>(zh, nullptr, fc1_h, nullptr, hbuf, nullptr, fc1_b,
                                              NROWS, CC, FFN, 8, F_BIAS1D | F_GELU | F_OUTB16);
        // savespace += h @ fc2^T + b  (2-term: h single plane, fc2 hi+lo)
        mm_k<0,1><<<2 * MT, 256, 0, stream>>>(hbuf, nullptr, fc2_h, fc2_l, out, nullptr, fc2_b,
                                              NROWS, FFN, CC, 2, F_BIAS1D | F_RESID);
    }
}